// Round 8
// baseline (520.040 us; speedup 1.0000x reference)
//
#include <hip/hip_runtime.h>

// RWKV v7 TimeMix forward, MI355X gfx950.
// B=8 T=2048 C=1024 H=16 D=64 DLOW=64. I/O f32, internal bf16 MFMA + f32 scan.
// R14: gemm256 un-pinned K-tile body: all ds_reads + 64 MFMA in ONE region with
//      NO manual lgkmcnt/sched_barrier (compiler emits counted lgkmcnt(N) and
//      interleaves LDS stream under MFMA stream); 2 barriers/K-tile
//      {compute | barrier | stage t+2 | vmcnt(8) | barrier}. Rest = R13
//      (XCD-local decode, FETCH 74MB). 6 launches.

typedef __bf16 bf16;
typedef __attribute__((ext_vector_type(8))) __bf16 bf16x8;
typedef __attribute__((ext_vector_type(4))) float f32x4;

#define TBTOK 16384   // B*T
#define TSEQ  2048
#define CDIM  1024
#define HN    16
#define CHUNK 32
#define NCH   64      // TSEQ / CHUNK

__device__ __forceinline__ float wredsum(float v) {
#pragma unroll
  for (int o = 32; o > 0; o >>= 1) v += __shfl_xor(v, o, 64);
  return v;
}
__device__ __forceinline__ float redsum8(float v) {  // 8 consecutive lanes
#pragma unroll
  for (int o = 4; o > 0; o >>= 1) v += __shfl_xor(v, o, 64);
  return v;
}
__device__ __forceinline__ float sigmf(float x) { return 1.f / (1.f + expf(-x)); }

// async global->LDS, 16 bytes/lane. LDS base wave-uniform (HW adds lane*16).
__device__ __forceinline__ void gl_lds16(const bf16* g, bf16* l) {
  __builtin_amdgcn_global_load_lds(
      (const __attribute__((address_space(1))) unsigned int*)g,
      (__attribute__((address_space(3))) unsigned int*)l, 16, 0, 0);
}

// ---------------- prep: mixcvt (blocks 0..8191) + all weight transposes ----------
__global__ __launch_bounds__(256) void prep_kern(
    const float* __restrict__ x, const float* __restrict__ mr,
    const float* __restrict__ mk, const float* __restrict__ mv,
    bf16* __restrict__ xr, bf16* __restrict__ xk, bf16* __restrict__ xv,
    bf16* __restrict__ xbf,
    const float* __restrict__ Wr, const float* __restrict__ Wk,
    const float* __restrict__ Wv, const float* __restrict__ Wo,
    const float* __restrict__ w1, const float* __restrict__ a1, const float* __restrict__ g1,
    const float* __restrict__ mw, const float* __restrict__ ma, const float* __restrict__ mg,
    const float* __restrict__ g2, const float* __restrict__ w2, const float* __restrict__ a2,
    bf16* __restrict__ WrT, bf16* __restrict__ WkT, bf16* __restrict__ WvT, bf16* __restrict__ WoT,
    bf16* __restrict__ Bcat, bf16* __restrict__ g2T,
    bf16* __restrict__ w2T, bf16* __restrict__ a2T, float* __restrict__ zpad) {
  int bid0 = blockIdx.x;
  int tid = threadIdx.x;
  if (bid0 < 8192) {
    long i8 = ((long)bid0 * 256 + tid) * 8;
    int m = (int)(i8 >> 10);
    int c = (int)(i8 & 1023);
    f32x4 x0 = *(const f32x4*)(x + i8);
    f32x4 x1 = *(const f32x4*)(x + i8 + 4);
    f32x4 p0 = {0.f, 0.f, 0.f, 0.f}, p1 = {0.f, 0.f, 0.f, 0.f};
    if ((m & (TSEQ - 1)) != 0) {
      p0 = *(const f32x4*)(x + i8 - CDIM);
      p1 = *(const f32x4*)(x + i8 - CDIM + 4);
    }
    f32x4 r0 = *(const f32x4*)(mr + c), r1 = *(const f32x4*)(mr + c + 4);
    f32x4 k0 = *(const f32x4*)(mk + c), k1 = *(const f32x4*)(mk + c + 4);
    f32x4 v0 = *(const f32x4*)(mv + c), v1 = *(const f32x4*)(mv + c + 4);
    bf16x8 or_, ok_, ov_, ox_;
#pragma unroll
    for (int j = 0; j < 4; j++) {
      float s0 = x0[j] - p0[j], s1 = x1[j] - p1[j];
      or_[j] = (bf16)(x0[j] + s0 * r0[j]); or_[4 + j] = (bf16)(x1[j] + s1 * r1[j]);
      ok_[j] = (bf16)(x0[j] + s0 * k0[j]); ok_[4 + j] = (bf16)(x1[j] + s1 * k1[j]);
      ov_[j] = (bf16)(x0[j] + s0 * v0[j]); ov_[4 + j] = (bf16)(x1[j] + s1 * v1[j]);
      ox_[j] = (bf16)x0[j];                ox_[4 + j] = (bf16)x1[j];
    }
    *(bf16x8*)(xr + i8) = or_;
    *(bf16x8*)(xk + i8) = ok_;
    *(bf16x8*)(xv + i8) = ov_;
    *(bf16x8*)(xbf + i8) = ox_;
    return;
  }
  int bid = bid0 - 8192;
  int tx = tid & 31, ty = tid >> 5;  // 32 x 8
  __shared__ bf16 tile[32][33];
  if (bid < 4096) {
    int sel = bid >> 10, t = bid & 1023;
    int k0 = (t >> 5) * 32, n0 = (t & 31) * 32;
    const float* src = sel == 0 ? Wr : (sel == 1 ? Wk : (sel == 2 ? Wv : Wo));
    bf16* dst = sel == 0 ? WrT : (sel == 1 ? WkT : (sel == 2 ? WvT : WoT));
#pragma unroll
    for (int i = 0; i < 4; i++)
      tile[ty + i * 8][tx] = (bf16)src[(long)(k0 + ty + i * 8) * 1024 + n0 + tx];
    __syncthreads();
#pragma unroll
    for (int i = 0; i < 4; i++)
      dst[(long)(n0 + ty + i * 8) * 1024 + k0 + tx] = tile[tx][ty + i * 8];
  } else if (bid < 4480) {
    int idx = bid - 4096;
    int mat = idx >> 7, rem = idx & 127;
    int half = rem >> 6, t = rem & 63;
    int k0 = (t >> 1) * 32, n0 = (t & 1) * 32;
    const float* W = mat == 0 ? w1 : (mat == 1 ? a1 : g1);
    const float* mx = mat == 0 ? mw : (mat == 1 ? ma : mg);
#pragma unroll
    for (int i = 0; i < 4; i++) {
      int k = k0 + ty + i * 8;
      float s = half == 0 ? (1.f + mx[k]) : (-mx[k]);
      tile[ty + i * 8][tx] = (bf16)(s * W[(long)k * 64 + n0 + tx]);
    }
    __syncthreads();
#pragma unroll
    for (int i = 0; i < 4; i++)
      Bcat[(long)(mat * 64 + n0 + ty + i * 8) * 2048 + half * 1024 + k0 + tx] =
          tile[tx][ty + i * 8];
  } else if (bid < 4544) {
    int t = bid - 4480;
    int k0 = (t >> 5) * 32, n0 = (t & 31) * 32;
#pragma unroll
    for (int i = 0; i < 4; i++)
      tile[ty + i * 8][tx] = (bf16)g2[(long)(k0 + ty + i * 8) * 1024 + n0 + tx];
    __syncthreads();
#pragma unroll
    for (int i = 0; i < 4; i++)
      g2T[(long)(n0 + ty + i * 8) * 64 + k0 + tx] = tile[tx][ty + i * 8];
  } else {
#pragma unroll
    for (int rep = 0; rep < 4; rep++) {
      int idx = rep * 256 + tid;  // 0..1023
      int k = idx >> 4, h = idx & 15;
      w2T[h * 64 + k] = (bf16)w2[idx];
      a2T[h * 64 + k] = (bf16)a2[idx];
    }
    if (tid < 64) zpad[tid] = 0.f;
  }
}

// ---------------- big GEMM: 256x256, BK=64, 8 waves, un-pinned K-tile body -----
// LDS: A/B half-tiles [2 dbuf][2 half][128x64] = 128 KiB. Per K-tile: one
// region {24 ds_read + 64 MFMA, compiler-scheduled with counted lgkmcnt ->
// LDS stream overlaps MFMA stream}, then barrier | stage t+2 into freed buf |
// vmcnt(8) (t+1 landed, in-order retire) | barrier. 2 barriers/K-tile.
// Decode: XCD-local, n fastest (A HBM-fetched once, B L2-resident).
#define BARRIER __builtin_amdgcn_s_barrier()
#define LGKM0                                              \
  do {                                                     \
    asm volatile("s_waitcnt lgkmcnt(0)" ::: "memory");     \
    __builtin_amdgcn_sched_barrier(0);                     \
  } while (0)

#define READ_A(HALFP, QM)                                                                \
  {                                                                                      \
    const bf16* _h = (HALFP);                                                            \
    _Pragma("unroll") for (int i = 0; i < 4; i++) {                                      \
      int ra = (QM)*64 + i * 16 + lr;                                                    \
      _Pragma("unroll") for (int ks = 0; ks < 2; ks++)                                   \
          af[i][ks] = *(const bf16x8*)&_h[ra * 64 + (((ks * 4 + quad) ^ (ra & 7)) * 8)]; \
    }                                                                                    \
  }

#define READ_B(HALFP, QN)                                                                \
  {                                                                                      \
    const bf16* _h = (HALFP);                                                            \
    _Pragma("unroll") for (int jj = 0; jj < 2; jj++) {                                   \
      int rb = bro + ((QN)*2 + jj) * 16 + lr;                                            \
      _Pragma("unroll") for (int ks = 0; ks < 2; ks++)                                   \
          bfr[(QN)*2 + jj][ks] =                                                         \
              *(const bf16x8*)&_h[rb * 64 + (((ks * 4 + quad) ^ (rb & 7)) * 8)];         \
    }                                                                                    \
  }

#define MFMA16(QM, QN)                                                            \
  _Pragma("unroll") for (int ks = 0; ks < 2; ks++)                                \
  _Pragma("unroll") for (int i = 0; i < 4; i++)                                   \
  _Pragma("unroll") for (int jj = 0; jj < 2; jj++)                                \
      acc[(QM)*4 + i][(QN)*2 + jj] = __builtin_amdgcn_mfma_f32_16x16x32_bf16(     \
          af[i][ks], bfr[(QN)*2 + jj][ks], acc[(QM)*4 + i][(QN)*2 + jj], 0, 0, 0);

template <typename OT>
__global__ __launch_bounds__(512, 2) void gemm256_kern(
    const bf16* __restrict__ A0, const bf16* __restrict__ A1, const bf16* __restrict__ A2,
    const bf16* __restrict__ BT0, const bf16* __restrict__ BT1, const bf16* __restrict__ BT2,
    OT* __restrict__ out0, OT* __restrict__ out1, OT* __restrict__ out2,
    int K) {
  int nwg = gridDim.x;            // multiple of 8 (768 rkv / 256 Wo)
  int id = blockIdx.x;
  int qq = nwg >> 3;
  int wg = (id & 7) * qq + (id >> 3);   // bijective XCD swizzle (contiguous chunk)
  int mat = wg >> 8;              // 256 blocks per mat
  int rem = wg & 255;
  int m0 = (rem >> 2) << 8;       // n fastest: 4 n-tiles of an m-panel adjacent
  int n0 = (rem & 3) << 8;
  const bf16* Am = mat == 0 ? A0 : (mat == 1 ? A1 : A2);
  const bf16* BTm = mat == 0 ? BT0 : (mat == 1 ? BT1 : BT2);
  OT* out = mat == 0 ? out0 : (mat == 1 ? out1 : out2);

  __shared__ bf16 Al[2][2][128 * 64];   // [dbuf][half] 64 KB
  __shared__ bf16 Bl[2][2][128 * 64];   // 64 KB

  int tid = threadIdx.x;
  int w = tid >> 6, lane = tid & 63, quad = lane >> 4, lr = lane & 15;
  int wr = w >> 2, wc = w & 3;       // 2M x 4N waves; per-wave out = 128x64
  int hb = wc >> 1, bro = (wc & 1) * 64;

  // staging: per thread covers rows (tid>>3), (tid>>3)+64 of a half-tile;
  // global column chunk pre-swizzled so linear LDS dest + swizzled read match.
  int swz = ((tid & 7) ^ ((tid >> 3) & 7)) * 8;
  const bf16* aBase = Am + (long)(m0 + (tid >> 3)) * K + swz;
  const bf16* bBase = BTm + (long)(n0 + (tid >> 3)) * K + swz;

  auto stgA = [&](int db, int h, int t) {
    const bf16* g = aBase + (long)(h * 128) * K + t * 64;
    bf16* l = &Al[db][h][0] + w * 512;
    gl_lds16(g, l);
    gl_lds16(g + (long)64 * K, l + 4096);
  };
  auto stgB = [&](int db, int h, int t) {
    const bf16* g = bBase + (long)(h * 128) * K + t * 64;
    bf16* l = &Bl[db][h][0] + w * 512;
    gl_lds16(g, l);
    gl_lds16(g + (long)64 * K, l + 4096);
  };

  const bf16* A0p = &Al[0][wr][0];
  const bf16* A1p = &Al[1][wr][0];
  const bf16* B0p = &Bl[0][hb][0];
  const bf16* B1p = &Bl[1][hb][0];

  f32x4 acc[8][4] = {};
  bf16x8 af[4][2], bfr[4][2];

  int NT = K >> 6;

  // prologue: tile0 (B,B,A,A) then tile1 (B,B,A,A); wait tile0, keep tile1 in flight
  stgB(0, 0, 0); stgB(0, 1, 0); stgA(0, 0, 0); stgA(0, 1, 0);
  stgB(1, 0, 1); stgB(1, 1, 1); stgA(1, 0, 1); stgA(1, 1, 1);
  asm volatile("s_waitcnt vmcnt(8)" ::: "memory");
  BARRIER;

#pragma unroll 1
  for (int t = 0; t < NT; t++) {
    int cur = t & 1;
    const bf16* Ab = cur ? A1p : A0p;
    const bf16* Bb = cur ? B1p : B0p;
    // ---- un-pinned compute region: compiler interleaves ds_reads and MFMAs
    //      with counted lgkmcnt; no manual waits, no sched_barrier ----
    READ_A(Ab, 0);
    READ_B(Bb, 0);
    READ_B(Bb, 1);
    __builtin_amdgcn_s_setprio(1);
    MFMA16(0, 0);
    MFMA16(0, 1);
    __builtin_amdgcn_s_setprio(0);
    READ_A(Ab, 1);
    __builtin_amdgcn_s_setprio(1);
    MFMA16(1, 0);
    MFMA16(1, 1);
    __builtin_amdgcn_s_setprio(0);
    // all reads of buf[cur] consumed by the MFMAs above
    BARRIER;
    if (t + 2 < NT) {
      stgB(cur, 0, t + 2); stgB(cur, 1, t + 2);
      stgA(cur, 0, t + 2); stgA(cur, 1, t + 2);
      // 8 just-issued t+2 loads outstanding => t+1 (older) fully landed
      asm volatile("s_waitcnt vmcnt(8)" ::: "memory");
    } else {
      asm volatile("s_waitcnt vmcnt(0)" ::: "memory");
    }
    BARRIER;
  }

#pragma unroll
  for (int i = 0; i < 8; i++)
#pragma unroll
    for (int j = 0; j < 4; j++)
#pragma unroll
      for (int rg = 0; rg < 4; rg++) {
        int row = m0 + wr * 128 + i * 16 + quad * 4 + rg;
        int col = n0 + wc * 64 + j * 16 + lr;
        out[(long)row * CDIM + col] = (OT)acc[i][j][rg];
      }
}

// ---------------- stage1: [x|xprev]@Bcat^T (192 cols), BK=64, 3-buffer pipeline ----
// 256 blocks x 256 thr (4 waves; wave w owns cols 48w..48w+47). K=2048 = 32 steps.
// Per step: 14 ds_read_b128, lgkm0, 24 MFMA, barrier, stage t+3 (8 gl_lds),
// vmcnt(16) (=> t+1 landed, 2-step cover), barrier. Swizzled [r][64] tiles.
// Epilogue: tanh -> Lt1 (cols<128) / t1g (cols>=128); then fused w/a dots.
__global__ __launch_bounds__(256) void stage1_kern(
    const bf16* __restrict__ xbf, const bf16* __restrict__ Bcat,
    const float* __restrict__ zpad, const bf16* __restrict__ w2T, const bf16* __restrict__ a2T,
    const float* __restrict__ w0, const float* __restrict__ a0,
    bf16* __restrict__ t1g, float* __restrict__ w_arr, float* __restrict__ a_arr) {
  int m0 = blockIdx.x * 64;
  __shared__ bf16 Abuf[3][64 * 64];    // 24 KB
  __shared__ bf16 Bbuf[3][192 * 64];   // 72 KB
  __shared__ bf16 Lt1[64 * 136];       // 17 KB

  int tid = threadIdx.x;
  int w = tid >> 6, lane = tid & 63, quad = lane >> 4, lr = lane & 15;

  // staging maps: A units = 64 rows x 8 slots; thread covers units tid, tid+256.
  int r0 = tid >> 3, s0 = tid & 7;
  int c0 = (s0 ^ (r0 & 7)) * 8;              // pre-swizzled column chunk
  const bf16* arow0 = xbf + (long)(m0 + r0) * CDIM + c0;
  const bf16* arow1 = xbf + (long)(m0 + 32 + r0) * CDIM + c0;
  bool fr0 = ((m0 + r0) & (TSEQ - 1)) == 0;  // true only for r0==0 at seq starts
  const bf16* aprev0 = fr0 ? ((const bf16*)zpad) : (arow0 - CDIM);
  const bf16* aprev1 = arow1 - CDIM;         // rows 32..63 never first-of-seq
  long pm0 = fr0 ? 0 : 64;
  // B units = 192 rows x 8 slots; thread covers units tid + j*256 (rows r0+32j)
  const bf16* brow = Bcat + (long)r0 * 2048 + c0;

  bf16* sA0 = &Abuf[0][0]; bf16* sA1 = &Abuf[1][0]; bf16* sA2 = &Abuf[2][0];
  bf16* sB0 = &Bbuf[0][0]; bf16* sB1 = &Bbuf[1][0]; bf16* sB2 = &Bbuf[2][0];

  auto stage = [&](bf16* sA, bf16* sB, int kk) {
    const bf16* a0s = (kk < 16) ? (arow0 + kk * 64) : (aprev0 + (long)(kk - 16) * pm0);
    const bf16* a1s = (kk < 16) ? (arow1 + kk * 64) : (aprev1 + (long)(kk - 16) * 64);
    gl_lds16(a0s, sA + w * 512);
    gl_lds16(a1s, sA + 2048 + w * 512);
    const bf16* bs = brow + kk * 64;
#pragma unroll
    for (int j = 0; j < 6; j++)
      gl_lds16(bs + (long)j * 32 * 2048, sB + j * 2048 + w * 512);
  };

  f32x4 acc[4][3] = {};

  stage(sA0, sB0, 0);
  stage(sA1, sB1, 1);
  stage(sA2, sB2, 2);
  asm volatile("s_waitcnt vmcnt(16)" ::: "memory");  // step0 landed
  BARRIER;

#pragma unroll 1
  for (int t = 0; t < 32; t++) {
    bf16x8 af[4][2], bfr[3][2];
#pragma unroll
    for (int i = 0; i < 4; i++) {
      int ra = i * 16 + lr;
#pragma unroll
      for (int ks = 0; ks < 2; ks++)
        af[i][ks] = *(const bf16x8*)&sA0[ra * 64 + (((ks * 4 + quad) ^ (ra & 7)) * 8)];
    }
#pragma unroll
    for (int n = 0; n < 3; n++) {
      int rb = w * 48 + n * 16 + lr;
#pragma unroll
      for (int ks = 0; ks < 2; ks++)
        bfr[n][ks] = *(const bf16x8*)&sB0[rb * 64 + (((ks * 4 + quad) ^ (rb & 7)) * 8)];
    }
    LGKM0;
    __builtin_amdgcn_s_setprio(1);
#pragma unroll
    for (int ks = 0; ks < 2; ks++)
#pragma unroll
      for (int i = 0; i < 4; i++)
#pragma unroll
        for (int n = 0; n < 3; n++)
          acc[i][n] = __builtin_amdgcn_mfma_f32_16x16x32_bf16(af[i][ks], bfr[n][ks],
                                                              acc[i][n], 0, 0, 0);
    __builtin_amdgcn_s_setprio(0);
    BARRIER;                       // all waves' reads of buf t%3 confirmed
    if (t + 3 < 32) {
      stage(sA0, sB0, t + 3);      // (t+3)%3 == t%3: reuse just-freed buffer
      asm volatile("s_waitcnt vmcnt(16)" ::: "memory");  // t+1 landed
    } else if (t == 29) {
      asm volatile("s_waitcnt vmcnt(8)" ::: "memory");
    } else if (t == 30) {
      asm volatile("s_waitcnt vmcnt(0)" ::: "memory");
    }
    BARRIER;
    bf16* tmpA = sA0; sA0 = sA1; sA1 = sA2; sA2 = tmpA;
    bf16* tmpB = sB0; sB0 = sB1; sB1 = sB2; sB2 = tmpB;
  }

  // epilogue: tanh -> Lt1 (w|a cols) / t1g (g cols)
#pragma unroll
  for (int i = 0; i < 4; i++)
#pragma unroll
    for (int n = 0; n < 3; n++) {
      int col = w * 48 + n * 16 + lr;
#pragma unroll
      for (int rg = 0; rg < 4; rg++) {
        int row = i * 16 + quad * 4 + rg;
        float tv = tanhf(acc[i][n][rg]);
        if (col < 128) Lt1[row * 136 + col] = (bf16)tv;
        else t1g[(long)(m0 + row) * 64 + (col - 128)] = (bf16)tv;
      }
    }
  __syncthreads();
#pragma unroll
  for (int rep = 0; rep < 4; rep++) {
    int idx = rep * 256 + tid;
    int row = idx >> 4, h = idx & 15;
    const bf16* rw = &Lt1[row * 136];
    const bf16* ra = rw + 64;
    const bf16* ww = w2T + h * 64;
    const bf16* aw = a2T + h * 64;
    float dw = 0.f, da = 0.f;
#pragma unroll
    for (int k = 0; k < 64; k++) {
      dw += (float)rw[k] * (float)ww[k];
      da += (float)ra[k] * (float)aw[k];
    }
    w_arr[h * TBTOK + m0 + row] = 0.60653066f * sigmf(w0[h] + dw);
    a_arr[h * TBTOK + m0 + row] = sigmf(a0[h] + da);
  }
}

// ---------------- scan1: fused prep + local 32-token scan; chunk-final -> Lend ------
// wave per (bh, chunk). 128 bh * 64 chunks = 8192 waves.
__global__ __launch_bounds__(256) void scan1_kern(
    const bf16* __restrict__ k_buf, const bf16* __restrict__ v_buf, const bf16* __restrict__ r_buf,
    const float* __restrict__ k_k, const float* __restrict__ r_k,
    const float* __restrict__ a_arr, const float* __restrict__ w_arr,
    float* __restrict__ kv2, float* __restrict__ Parr, float* __restrict__ bonus,
    float* __restrict__ Lend) {
  int wid = blockIdx.x * 4 + (threadIdx.x >> 6);
  int lane = threadIdx.x & 63;
  int bh = wid >> 6, c = wid & 63;
  int b = bh >> 4, h = bh & 15;
  int mstart = b * TSEQ + c * CHUNK;
  int kc = h * 64 + lane;
  float kkc = k_k[kc], rkc = r_k[kc];
  float st = 0.f, cw = 1.f;
  long mbase = (long)mstart * CDIM + kc;
  int hm = h * TBTOK + mstart;
  long sbase = ((long)hm) * 64 + lane;
  float kf = (float)k_buf[mbase] * kkc;
  float vf = (float)v_buf[mbase];
  float rf = (float)r_buf[mbase];
  float af = a_arr[hm];
  float wt = w_arr[hm];
  for (int t = 0; t < CHUNK; t++) {
    float kf_n = 0.f, vf_n = 0.f, rf_n = 0.f, af_n = 0.f, wt_n = 0.f;
    if (t < CHUNK - 1) {
      kf_n = (float)k_buf[mbase + CDIM] * kkc;
      vf_n = (float)v_buf[mbase + CDIM];
      rf_n = (float)r_buf[mbase + CDIM];
      af_n = a_arr[hm + 1];
      wt_n = w_arr[hm + 1];
    }
    float ss = wredsum(kf * kf);
    float kkn = kf / fmaxf(sqrtf(ss), 1e-12f);
    st = st * wt + kkn * vf * af;
    kv2[sbase] = st;
    cw *= wt;
    float bs = wredsum(rf * kkn * rkc);
    if (lane == 0) {
      Parr[hm] = cw;
      bonus[(mstart + t) * HN + h] = bs;
    }
    kf = kf_n; vf = vf_n; rf = rf_n; af = af_n; wt = wt_n;
    mbase += CDIM; hm += 1; sbase += 64;
  }
  // carry entering next chunk == this chunk's final state (P_chunk <= e^-16)
  Lend[(long)wid * 64 + lane] = st;
}

// ---------------- gate_post: g=sigmoid(t1g@g2) -> LDS; vectorized fixup+groupnorm ----
__global__ __launch_bounds__(256) void gate_post_kern(
    const bf16* __restrict__ t1g, const bf16* __restrict__ g2T,
    const float* __restrict__ kv2, const float* __restrict__ Parr,
    const float* __restrict__ Lend, const float* __restrict__ bonus,
    bf16* __restrict__ r_buf, const bf16* __restrict__ v_buf,
    const float* __restrict__ ln_w, const float* __restrict__ ln_b) {
  int ncol0 = blockIdx.x * 128;
  int m0 = blockIdx.y * 128;

  __shared__ bf16 Al[128 * 32];       // 8 KB
  __shared__ bf16 Bl[128 * 32];       // 8 KB
  __shared__ bf16 gtile[128 * 136];   // 34 KB

  int tid = threadIdx.x;
  int w = tid >> 6, lane = tid & 63, quad = lane >> 4, lr = lane & 15;
  int wm = (w & 1) * 64, wn = (w >> 1) * 64;

  f32x4 acc[4][4] = {};

  int r0 = tid >> 2, kc0 = (tid & 3) * 8;
  const bf16* ag0 = t1g + (long)(m0 + r0) * 64 + kc0;
  const bf16* ag1 = ag0 + (long)64 * 64;
  const bf16* bg0 = g2T + (long)(ncol0 + r0) * 64 + kc0;
  const bf16* bg1 = bg0 + (long)64 * 64;
  bf16* la0 = Al + w * 512;
  bf16* la1 = Al + 2048 + w * 512;
  bf16* lb0 = Bl + w * 512;
  bf16* lb1 = Bl + 2048 + w * 512;

  for (int k0 = 0; k0 < 64; k0 += 32) {
    gl_lds16(ag0, la0);
    gl_lds16(ag1, la1);
    gl_lds16(bg0, lb0);
    gl_lds16(bg1, lb1);
    ag0 += 32; ag1 += 32; bg0 += 32; bg1 += 32;
    __syncthreads();
    bf16x8 af[4], bff[4];
#pragma unroll
    for (int i = 0; i < 4; i++) af[i] = *(const bf16x8*)&Al[(wm + i * 16 + lr) * 32 + quad * 8];
#pragma unroll
    for (int j = 0; j < 4; j++) bff[j] = *(const bf16x8*)&Bl[(wn + j * 16 + lr) * 32 + quad * 8];
#pragma unroll
    for (int i = 0; i < 4; i++)
#pragma unroll
      for (int j = 0; j < 4; j++)
        acc[i][j] = __builtin_amdgcn_mfma_f32_16x16x32_bf16(af[i], bff[j], acc[i][j], 0, 0, 0);
    __syncthreads();
  }
  // phase 1b: sigmoid(gate) -> LDS tile in C-layout
#pragma unroll
  for (int i = 0; i < 4; i++)
#pragma unroll
    for (int j = 0; j < 4; j++)
#pragma unroll
      for (int rg = 0; rg < 4; rg++) {
        int row = wm + i * 16 + quad * 4 + rg;
        int col = wn + j * 16 + lr;
        gtile[row * 136 + col] = (bf16)sigmf(acc[i][j][rg]);
      }
  __syncthreads();

  // phase 2: 8 contiguous channels per thread; fully vectorized global access
  int c_loc = (tid & 15) * 8;            // 0..120
  int col_g = ncol0 + c_loc;
  int h = col_g >> 6;
  int d0 = col_g & 63;
  f32x4 lnw0 = *(const f32x4*)(ln_w + col_g);
  f32x4 lnw1 = *(const f32x4*)(ln_w + col_g + 4);
  f32x4 lnb0 = *(const f32x4*)(ln_b + col_g);
  f32x4 lnb1 = *(const f32x4*)(ln_b + col_g + 4);
#pragma unroll
  for (int jj = 0; jj < 8; jj++) {
    int row = jj * 16 + (tid >> 4);
    int row_g = m0 + row;
    int b = row_g >> 11;
    int ch = (row_g & (TSEQ - 1)) >> 5;
    long kvb = ((long)h * TBTOK + row_g) * 64 + d0;
    f32x4 st0 = *(const f32x4*)(kv2 + kvb);
    f32x4 st1 = *(const f32x4*)(kv2 + kvb + 4);
    f32x4 cy0 = {0.f, 0.f, 0.f, 0.f}, cy1 = {0.f, 0.f, 0.f, 0.f};
    if (ch != 0) {
      long lb = ((long)((b * 16 + h) * NCH + ch - 1)) * 64 + d0;
      cy0 = *(const f32x4*)(Lend + lb);
      cy1 = *(const f32x4*)(Lend + lb + 4);
    }
    float pw = Parr[h * TBTOK + row_g];
    float bs = bonus[row_g * HN + h];
    long rb = (long)row_g * CDIM + col_g;
    bf16x8 rf8 = *(const bf16x8*)(r_buf + rb);
    bf16x8 vf8 = *(const bf16x8*)(v_buf + rb);
    bf16x8 g8 = *(const bf16x8*)&gtile[row * 136 + c_loc];
    float xw[8];
#pragma unroll
    for (int q = 0; q < 4; q++) {
      xw[q]     = (st0[q] + pw * cy0[q]) * (float)rf8[q]     + bs * (float)vf8[q];
      xw[4 + q] = (st1[q] + pw * cy1[q]) * (float)rf8[4 + q] + bs * (float)vf8[4 + q];
    }
    float sum = 0.f;
#pragma unroll
    for (int q = 0; q < 8; q++) sum += xw[q];
    float mn = redsum8(sum) * (1.f / 64.f);
    float vs = 0.f;
#pragma unroll
    for (int q = 0; q < 8; q++) {
      xw[q] -= mn;
      vs += xw[q] * xw[q];
    }
    float var = redsum8(vs) * (1.f / 64.f);
    float rq = rsqrtf(var + 1e-5f);
    bf16x8 o8;
#pragma unroll
    for (int q = 0; q < 4; q++) {
      o8[q]     = (bf16)((xw[q] * rq * lnw0[q] + lnb0[q]) * (float)g8[q]);
      o8[4 + q] = (bf16)((xw[4 + q] * rq * lnw1[q] + lnb1[q]) * (float)g8[4 + q]);
    }
    *(bf16x8*)(r_buf + rb) = o8;
  }
}

extern "C" void kernel_launch(void* const* d_in, const int* in_sizes, int n_in,
                              void* d_out, int out_size, void* d_ws, size_t ws_size,
                              hipStream_t stream) {
  const float* x    = (const float*)d_in[0];
  const float* x_r  = (const float*)d_in[1];
  const float* x_w  = (const float*)d_in[2];
  const float* x_k  = (const float*)d_in[3];
  const float* x_v  = (const float*)d_in[4];
  const float* x_a  = (const float*)d_in[5];
  const float* x_g  = (const float*)d_in[6];
  const float* w0   = (const float*)d_in[7];
  const float* w1   = (const float*)d_in[8];
  const float* w2   = (const float*)d_in[9];
  const float* a0   = (const float*)d_in[10];
  const float* a1   = (const float*)d_in[11];
  const float* a2   = (const float*)d_in[12];
  // v0,v1,v2 (13,14,15) unused: v_res_gate is a no-op in the reference
  const float* g1   = (const float*)d_in[16];
  const float* g2   = (const float*)d_in[17];
  const float* k_k  = (const float*)d_in[18];
  const float* r_k  = (const float*)d_in[19];
  const float* Wr   = (const float*)d_in[20];
  const float* Wk   = (const float*)d_in[21];
  const float* Wv   = (const float*)d_in[22];
  const float* Wo   = (const float*)d_in[23];
  const float* ln_w = (const float*)d_in[24];
  const float* ln_b = (const float*)d_in[25];
  float* out = (float*)d_out;

  char* p = (char*)d_ws;
  auto carve = [&](size_t bytes) {
    void* r = (void*)p;
    p += (bytes + 255) & ~(size_t)255;
    return r;
  };
  bf16* WrT = (bf16*)carve(1024 * 1024 * 2);
  bf16* WkT = (bf16*)carve(1024 * 1024 * 2);
  bf16* WvT = (bf16*)carve(1024 * 1024 * 2);
  bf16* WoT = (bf16*)carve(1024 * 1024 * 2);
  bf16* Bcat = (bf16*)carve(192 * 2048 * 2);
  bf16* g2T  = (bf16*)carve(1024 * 64 * 2);
  bf16* w2T  = (bf16*)carve(16 * 64 * 2);
  bf16* a2T  = (bf16*)carve(16 * 64 * 2);
  float* zpad = (float*)carve(64 * 4);
  bf16* t1g   = (bf16*)carve((size_t)TBTOK * 64 * 2);
  bf16* r_buf = (bf16*)carve((size_t)TBTOK * CDIM * 2);
  bf16* k_buf = (bf16*)carve((size_t)TBTOK * CDIM * 2);
  bf16* v_buf = (bf16*)carve((size_t)TBTOK * CDIM * 2);
  float* w_arr = (float*)carve((size_t)TBTOK * HN * 4);
  float* a_arr = (float*)carve((size_t)TBTOK * HN * 4);
  float* bonus = (float*)carve((size_t)TBTOK * HN * 4);
  float* Parr  = (float*)carve((size_t)TBTOK * HN * 4);
  float* Lend  = (float*)carve((size_t)128 * NCH * 64 * 4);
  bf16* xr  = (bf16*)carve((size_t)TBTOK * CDIM * 2);
  bf16* xk  = (bf16*)carve((size_t)TBTOK * CDIM * 2);
  bf16* xv  = (bf16*)carve((size_t)TBTOK * CDIM * 2);
  bf16* xbf = (bf16*)carve((size_t)TBTOK * CDIM * 2);
  float* kv2 = (float*)xv;  // 64MB = xv+xbf, dead before scan1

  // 1. mixcvt + all weight prep
  prep_kern<<<dim3(8192 + 4545), 256, 0, stream>>>(
      x, x_r, x_k, x_v, xr, xk, xv, xbf,
      Wr, Wk, Wv, Wo, w1, a1, g1, x_w, x_a, x_g, g2, w2, a2,
      WrT, WkT, WvT, WoT, Bcat, g2T, w2T, a2T, zpad);
  // 2. LoRA stage1 (merged 192-col GEMM + fused stage2 dots)
  stage1_kern<<<dim3(TBTOK / 64), 256, 0, stream>>>(
      xbf, Bcat, zpad, w2T, a2T, w0, a0, t1g, w_arr, a_arr);
  // 3. r,k,v projections: 768 blocks, XCD-local n-fastest decode.
  gemm256_kern<bf16><<<dim3(768), 512, 0, stream>>>(
      xr, xk, xv, WrT, WkT, WvT, r_buf, k_buf, v_buf, 1024);
  // 4. WKV local scans (CHUNK=32; carry == prev chunk-final state)
  scan1_kern<<<dim3(128 * NCH / 4), 256, 0, stream>>>(
      k_buf, v_buf, r_buf, k_k, r_k, a_arr, w_arr, kv2, Parr, bonus, Lend);
  // 5. gate GEMM + vectorized fixup/groupnorm/gating -> an (into r_buf)
  gate_post_kern<<<dim3(8, TBTOK / 128), 256, 0, stream>>>(
      t1g, g2T, kv2, Parr, Lend, bonus, r_buf, v_buf, ln_w, ln_b);
  // 6. out = an @ Wo  (f32 output)
  gemm256_kern<float><<<dim3(256), 512, 0, stream>>>(
      r_buf, r_buf, r_buf, WoT, WoT, WoT, out, out, out, 1024);
}

// Round 9
// 516.636 us; speedup vs baseline: 1.0066x; 1.0066x over previous
//
#include <hip/hip_runtime.h>

// RWKV v7 TimeMix forward, MI355X gfx950.
// B=8 T=2048 C=1024 H=16 D=64 DLOW=64. I/O f32, internal bf16 MFMA + f32 scan.
// R15: R13 choreography (best measured: single-barrier 4-phase/K-tile, pinned
//      LGKM0, XCD-local decode) with 32x32x16 MFMA instead of 16x16x32:
//      halves MFMA instruction count (m119: 2495 vs 2075 TF ceiling), same
//      LDS traffic/swizzle/registers. C/D layout per m74/m101. 6 launches.

typedef __bf16 bf16;
typedef __attribute__((ext_vector_type(8))) __bf16 bf16x8;
typedef __attribute__((ext_vector_type(4))) float f32x4;
typedef __attribute__((ext_vector_type(16))) float f32x16;

#define TBTOK 16384   // B*T
#define TSEQ  2048
#define CDIM  1024
#define HN    16
#define CHUNK 32
#define NCH   64      // TSEQ / CHUNK

__device__ __forceinline__ float wredsum(float v) {
#pragma unroll
  for (int o = 32; o > 0; o >>= 1) v += __shfl_xor(v, o, 64);
  return v;
}
__device__ __forceinline__ float redsum8(float v) {  // 8 consecutive lanes
#pragma unroll
  for (int o = 4; o > 0; o >>= 1) v += __shfl_xor(v, o, 64);
  return v;
}
__device__ __forceinline__ float sigmf(float x) { return 1.f / (1.f + expf(-x)); }

// async global->LDS, 16 bytes/lane. LDS base wave-uniform (HW adds lane*16).
__device__ __forceinline__ void gl_lds16(const bf16* g, bf16* l) {
  __builtin_amdgcn_global_load_lds(
      (const __attribute__((address_space(1))) unsigned int*)g,
      (__attribute__((address_space(3))) unsigned int*)l, 16, 0, 0);
}

// ---------------- prep: mixcvt (blocks 0..8191) + all weight transposes ----------
__global__ __launch_bounds__(256) void prep_kern(
    const float* __restrict__ x, const float* __restrict__ mr,
    const float* __restrict__ mk, const float* __restrict__ mv,
    bf16* __restrict__ xr, bf16* __restrict__ xk, bf16* __restrict__ xv,
    bf16* __restrict__ xbf,
    const float* __restrict__ Wr, const float* __restrict__ Wk,
    const float* __restrict__ Wv, const float* __restrict__ Wo,
    const float* __restrict__ w1, const float* __restrict__ a1, const float* __restrict__ g1,
    const float* __restrict__ mw, const float* __restrict__ ma, const float* __restrict__ mg,
    const float* __restrict__ g2, const float* __restrict__ w2, const float* __restrict__ a2,
    bf16* __restrict__ WrT, bf16* __restrict__ WkT, bf16* __restrict__ WvT, bf16* __restrict__ WoT,
    bf16* __restrict__ Bcat, bf16* __restrict__ g2T,
    bf16* __restrict__ w2T, bf16* __restrict__ a2T, float* __restrict__ zpad) {
  int bid0 = blockIdx.x;
  int tid = threadIdx.x;
  if (bid0 < 8192) {
    long i8 = ((long)bid0 * 256 + tid) * 8;
    int m = (int)(i8 >> 10);
    int c = (int)(i8 & 1023);
    f32x4 x0 = *(const f32x4*)(x + i8);
    f32x4 x1 = *(const f32x4*)(x + i8 + 4);
    f32x4 p0 = {0.f, 0.f, 0.f, 0.f}, p1 = {0.f, 0.f, 0.f, 0.f};
    if ((m & (TSEQ - 1)) != 0) {
      p0 = *(const f32x4*)(x + i8 - CDIM);
      p1 = *(const f32x4*)(x + i8 - CDIM + 4);
    }
    f32x4 r0 = *(const f32x4*)(mr + c), r1 = *(const f32x4*)(mr + c + 4);
    f32x4 k0 = *(const f32x4*)(mk + c), k1 = *(const f32x4*)(mk + c + 4);
    f32x4 v0 = *(const f32x4*)(mv + c), v1 = *(const f32x4*)(mv + c + 4);
    bf16x8 or_, ok_, ov_, ox_;
#pragma unroll
    for (int j = 0; j < 4; j++) {
      float s0 = x0[j] - p0[j], s1 = x1[j] - p1[j];
      or_[j] = (bf16)(x0[j] + s0 * r0[j]); or_[4 + j] = (bf16)(x1[j] + s1 * r1[j]);
      ok_[j] = (bf16)(x0[j] + s0 * k0[j]); ok_[4 + j] = (bf16)(x1[j] + s1 * k1[j]);
      ov_[j] = (bf16)(x0[j] + s0 * v0[j]); ov_[4 + j] = (bf16)(x1[j] + s1 * v1[j]);
      ox_[j] = (bf16)x0[j];                ox_[4 + j] = (bf16)x1[j];
    }
    *(bf16x8*)(xr + i8) = or_;
    *(bf16x8*)(xk + i8) = ok_;
    *(bf16x8*)(xv + i8) = ov_;
    *(bf16x8*)(xbf + i8) = ox_;
    return;
  }
  int bid = bid0 - 8192;
  int tx = tid & 31, ty = tid >> 5;  // 32 x 8
  __shared__ bf16 tile[32][33];
  if (bid < 4096) {
    int sel = bid >> 10, t = bid & 1023;
    int k0 = (t >> 5) * 32, n0 = (t & 31) * 32;
    const float* src = sel == 0 ? Wr : (sel == 1 ? Wk : (sel == 2 ? Wv : Wo));
    bf16* dst = sel == 0 ? WrT : (sel == 1 ? WkT : (sel == 2 ? WvT : WoT));
#pragma unroll
    for (int i = 0; i < 4; i++)
      tile[ty + i * 8][tx] = (bf16)src[(long)(k0 + ty + i * 8) * 1024 + n0 + tx];
    __syncthreads();
#pragma unroll
    for (int i = 0; i < 4; i++)
      dst[(long)(n0 + ty + i * 8) * 1024 + k0 + tx] = tile[tx][ty + i * 8];
  } else if (bid < 4480) {
    int idx = bid - 4096;
    int mat = idx >> 7, rem = idx & 127;
    int half = rem >> 6, t = rem & 63;
    int k0 = (t >> 1) * 32, n0 = (t & 1) * 32;
    const float* W = mat == 0 ? w1 : (mat == 1 ? a1 : g1);
    const float* mx = mat == 0 ? mw : (mat == 1 ? ma : mg);
#pragma unroll
    for (int i = 0; i < 4; i++) {
      int k = k0 + ty + i * 8;
      float s = half == 0 ? (1.f + mx[k]) : (-mx[k]);
      tile[ty + i * 8][tx] = (bf16)(s * W[(long)k * 64 + n0 + tx]);
    }
    __syncthreads();
#pragma unroll
    for (int i = 0; i < 4; i++)
      Bcat[(long)(mat * 64 + n0 + ty + i * 8) * 2048 + half * 1024 + k0 + tx] =
          tile[tx][ty + i * 8];
  } else if (bid < 4544) {
    int t = bid - 4480;
    int k0 = (t >> 5) * 32, n0 = (t & 31) * 32;
#pragma unroll
    for (int i = 0; i < 4; i++)
      tile[ty + i * 8][tx] = (bf16)g2[(long)(k0 + ty + i * 8) * 1024 + n0 + tx];
    __syncthreads();
#pragma unroll
    for (int i = 0; i < 4; i++)
      g2T[(long)(n0 + ty + i * 8) * 64 + k0 + tx] = tile[tx][ty + i * 8];
  } else {
#pragma unroll
    for (int rep = 0; rep < 4; rep++) {
      int idx = rep * 256 + tid;  // 0..1023
      int k = idx >> 4, h = idx & 15;
      w2T[h * 64 + k] = (bf16)w2[idx];
      a2T[h * 64 + k] = (bf16)a2[idx];
    }
    if (tid < 64) zpad[tid] = 0.f;
  }
}

// ---------------- big GEMM: 256x256, BK=64, 8 waves, 32x32x16 MFMA --------------
// R13 choreography: 4 single-barrier phases per K-tile; stage B at P2, A at P3;
// vmcnt(8) at P3/P7-equivalent => prior tile landed. 32x32x16 fragments:
// A: lane l holds row (l&31), k=(l>>5)*8+j (8 contiguous bf16 -> b128 read,
// same XOR swizzle); C/D: col=lane&31, row=(reg&3)+8*(reg>>2)+4*(lane>>5).
// Per wave per K-tile: 24 ds_read_b128 (unchanged), 32 MFMA (was 64).
#define BARRIER __builtin_amdgcn_s_barrier()
#define LGKM0                                              \
  do {                                                     \
    asm volatile("s_waitcnt lgkmcnt(0)" ::: "memory");     \
    __builtin_amdgcn_sched_barrier(0);                     \
  } while (0)

// QM in {0,1}: A rows [QM*64, QM*64+64) of this wave's 128-row half (2 mb of 32)
#define READ_A32(HALFP, QM)                                                               \
  {                                                                                       \
    const bf16* _h = (HALFP);                                                             \
    _Pragma("unroll") for (int mb2 = 0; mb2 < 2; mb2++) {                                 \
      int ra = (QM)*64 + mb2 * 32 + l31;                                                  \
      _Pragma("unroll") for (int kc = 0; kc < 4; kc++) {                                  \
        int c = kc * 2 + l5;                                                              \
        af[mb2][kc] = *(const bf16x8*)&_h[ra * 64 + ((c ^ (ra & 7)) * 8)];                \
      }                                                                                   \
    }                                                                                     \
  }

// QN in {0,1}: B rows (=out cols) [bro+QN*32, bro+QN*32+32)
#define READ_B32(HALFP, QN)                                                               \
  {                                                                                       \
    const bf16* _h = (HALFP);                                                             \
    int rb = bro + (QN)*32 + l31;                                                         \
    _Pragma("unroll") for (int kc = 0; kc < 4; kc++) {                                    \
      int c = kc * 2 + l5;                                                                \
      bfr[QN][kc] = *(const bf16x8*)&_h[rb * 64 + ((c ^ (rb & 7)) * 8)];                  \
    }                                                                                     \
  }

#define MFMA32(QM, QN)                                                            \
  __builtin_amdgcn_s_setprio(1);                                                  \
  _Pragma("unroll") for (int kc = 0; kc < 4; kc++)                                \
  _Pragma("unroll") for (int mb2 = 0; mb2 < 2; mb2++)                             \
      acc[(QM)*2 + mb2][QN] = __builtin_amdgcn_mfma_f32_32x32x16_bf16(            \
          af[mb2][kc], bfr[QN][kc], acc[(QM)*2 + mb2][QN], 0, 0, 0);              \
  __builtin_amdgcn_s_setprio(0);

template <typename OT>
__global__ __launch_bounds__(512, 2) void gemm256_kern(
    const bf16* __restrict__ A0, const bf16* __restrict__ A1, const bf16* __restrict__ A2,
    const bf16* __restrict__ BT0, const bf16* __restrict__ BT1, const bf16* __restrict__ BT2,
    OT* __restrict__ out0, OT* __restrict__ out1, OT* __restrict__ out2,
    int K) {
  int nwg = gridDim.x;            // multiple of 8 (768 rkv / 256 Wo)
  int id = blockIdx.x;
  int qq = nwg >> 3;
  int wg = (id & 7) * qq + (id >> 3);   // bijective XCD swizzle (contiguous chunk)
  int mat = wg >> 8;              // 256 blocks per mat
  int rem = wg & 255;
  int m0 = (rem >> 2) << 8;       // n fastest: 4 n-tiles of an m-panel adjacent
  int n0 = (rem & 3) << 8;
  const bf16* Am = mat == 0 ? A0 : (mat == 1 ? A1 : A2);
  const bf16* BTm = mat == 0 ? BT0 : (mat == 1 ? BT1 : BT2);
  OT* out = mat == 0 ? out0 : (mat == 1 ? out1 : out2);

  __shared__ bf16 Al[2][2][128 * 64];   // [dbuf][half] 64 KB
  __shared__ bf16 Bl[2][2][128 * 64];   // 64 KB

  int tid = threadIdx.x;
  int w = tid >> 6, lane = tid & 63;
  int l31 = lane & 31, l5 = lane >> 5;
  int wr = w >> 2, wc = w & 3;       // 2M x 4N waves; per-wave out = 128x64
  int hb = wc >> 1, bro = (wc & 1) * 64;

  // staging: per thread covers rows (tid>>3), (tid>>3)+64 of a half-tile;
  // global column chunk pre-swizzled so linear LDS dest + swizzled read match.
  int swz = ((tid & 7) ^ ((tid >> 3) & 7)) * 8;
  const bf16* aBase = Am + (long)(m0 + (tid >> 3)) * K + swz;
  const bf16* bBase = BTm + (long)(n0 + (tid >> 3)) * K + swz;

  auto stgA = [&](int db, int h, int t) {
    const bf16* g = aBase + (long)(h * 128) * K + t * 64;
    bf16* l = &Al[db][h][0] + w * 512;
    gl_lds16(g, l);
    gl_lds16(g + (long)64 * K, l + 4096);
  };
  auto stgB = [&](int db, int h, int t) {
    const bf16* g = bBase + (long)(h * 128) * K + t * 64;
    bf16* l = &Bl[db][h][0] + w * 512;
    gl_lds16(g, l);
    gl_lds16(g + (long)64 * K, l + 4096);
  };

  const bf16* A0p = &Al[0][wr][0];
  const bf16* A1p = &Al[1][wr][0];
  const bf16* B0p = &Bl[0][hb][0];
  const bf16* B1p = &Bl[1][hb][0];

  f32x16 acc[4][2] = {};           // [mb][nb] 32x32 tiles; 128 VGPR
  bf16x8 af[2][4], bfr[2][4];

  int NT = K >> 6, NU = NT >> 1;

  // prologue: tile0 (B,B,A,A) then tile1 (B,B,A,A); wait tile0, keep tile1 in flight
  stgB(0, 0, 0); stgB(0, 1, 0); stgA(0, 0, 0); stgA(0, 1, 0);
  stgB(1, 0, 1); stgB(1, 1, 1); stgA(1, 0, 1); stgA(1, 1, 1);
  asm volatile("s_waitcnt vmcnt(8)" ::: "memory");
  BARRIER;

#pragma unroll 1
  for (int u = 0; u < NU; u++) {
    int t2 = 2 * u + 2, t3 = 2 * u + 3;
    // ---- P0: tile t0 quad (0,0) ----
    READ_A32(A0p, 0);
    READ_B32(B0p, 0);
    LGKM0;
    MFMA32(0, 0);
    BARRIER;
    // ---- P1: quad (0,1) ----
    READ_B32(B0p, 1);
    LGKM0;
    MFMA32(0, 1);
    BARRIER;
    // ---- P2: quad (1,1); stage B(t2) (dbuf0-B last read P1, barrier passed) ----
    READ_A32(A0p, 1);
    if (t2 < NT) { stgB(0, 0, t2); stgB(0, 1, t2); }
    LGKM0;
    MFMA32(1, 1);
    BARRIER;
    // ---- P3: stage A(t2) (dbuf0-A last read P2); MFMA on P2/P0 regs;
    //      vmcnt(8): 8 just-issued t2 loads outstanding => t1 landed ----
    if (t2 < NT) { stgA(0, 0, t2); stgA(0, 1, t2); }
    __builtin_amdgcn_sched_barrier(0);
    MFMA32(1, 0);
    if (t2 < NT) { asm volatile("s_waitcnt vmcnt(8)" ::: "memory"); }
    else         { asm volatile("s_waitcnt vmcnt(0)" ::: "memory"); }
    BARRIER;
    // ---- P4: tile t1 quad (0,0) ----
    READ_A32(A1p, 0);
    READ_B32(B1p, 0);
    LGKM0;
    MFMA32(0, 0);
    BARRIER;
    // ---- P5: quad (0,1) ----
    READ_B32(B1p, 1);
    LGKM0;
    MFMA32(0, 1);
    BARRIER;
    // ---- P6: quad (1,1); stage B(t3) ----
    READ_A32(A1p, 1);
    if (t3 < NT) { stgB(1, 0, t3); stgB(1, 1, t3); }
    LGKM0;
    MFMA32(1, 1);
    BARRIER;
    // ---- P7: stage A(t3); vmcnt(8) => t2 landed ----
    if (t3 < NT) { stgA(1, 0, t3); stgA(1, 1, t3); }
    __builtin_amdgcn_sched_barrier(0);
    MFMA32(1, 0);
    if (t3 < NT) { asm volatile("s_waitcnt vmcnt(8)" ::: "memory"); }
    else         { asm volatile("s_waitcnt vmcnt(0)" ::: "memory"); }
    BARRIER;
  }

  // epilogue: 32x32 C/D layout col=lane&31, row=(reg&3)+8*(reg>>2)+4*(lane>>5)
#pragma unroll
  for (int mb = 0; mb < 4; mb++)
#pragma unroll
    for (int nb = 0; nb < 2; nb++)
#pragma unroll
      for (int rg = 0; rg < 16; rg++) {
        int row = m0 + wr * 128 + mb * 32 + (rg & 3) + 8 * (rg >> 2) + 4 * l5;
        int col = n0 + wc * 64 + nb * 32 + l31;
        out[(long)row * CDIM + col] = (OT)acc[mb][nb][rg];
      }
}

// ---------------- stage1: [x|xprev]@Bcat^T (192 cols), BK=64, 3-buffer pipeline ----
// 256 blocks x 256 thr (4 waves; wave w owns cols 48w..48w+47). K=2048 = 32 steps.
// Per step: 14 ds_read_b128, lgkm0, 24 MFMA, barrier, stage t+3 (8 gl_lds),
// vmcnt(16) (=> t+1 landed, 2-step cover), barrier. Swizzled [r][64] tiles.
// Epilogue: tanh -> Lt1 (cols<128) / t1g (cols>=128); then fused w/a dots.
__global__ __launch_bounds__(256) void stage1_kern(
    const bf16* __restrict__ xbf, const bf16* __restrict__ Bcat,
    const float* __restrict__ zpad, const bf16* __restrict__ w2T, const bf16* __restrict__ a2T,
    const float* __restrict__ w0, const float* __restrict__ a0,
    bf16* __restrict__ t1g, float* __restrict__ w_arr, float* __restrict__ a_arr) {
  int m0 = blockIdx.x * 64;
  __shared__ bf16 Abuf[3][64 * 64];    // 24 KB
  __shared__ bf16 Bbuf[3][192 * 64];   // 72 KB
  __shared__ bf16 Lt1[64 * 136];       // 17 KB

  int tid = threadIdx.x;
  int w = tid >> 6, lane = tid & 63, quad = lane >> 4, lr = lane & 15;

  // staging maps: A units = 64 rows x 8 slots; thread covers units tid, tid+256.
  int r0 = tid >> 3, s0 = tid & 7;
  int c0 = (s0 ^ (r0 & 7)) * 8;              // pre-swizzled column chunk
  const bf16* arow0 = xbf + (long)(m0 + r0) * CDIM + c0;
  const bf16* arow1 = xbf + (long)(m0 + 32 + r0) * CDIM + c0;
  bool fr0 = ((m0 + r0) & (TSEQ - 1)) == 0;  // true only for r0==0 at seq starts
  const bf16* aprev0 = fr0 ? ((const bf16*)zpad) : (arow0 - CDIM);
  const bf16* aprev1 = arow1 - CDIM;         // rows 32..63 never first-of-seq
  long pm0 = fr0 ? 0 : 64;
  // B units = 192 rows x 8 slots; thread covers units tid + j*256 (rows r0+32j)
  const bf16* brow = Bcat + (long)r0 * 2048 + c0;

  bf16* sA0 = &Abuf[0][0]; bf16* sA1 = &Abuf[1][0]; bf16* sA2 = &Abuf[2][0];
  bf16* sB0 = &Bbuf[0][0]; bf16* sB1 = &Bbuf[1][0]; bf16* sB2 = &Bbuf[2][0];

  auto stage = [&](bf16* sA, bf16* sB, int kk) {
    const bf16* a0s = (kk < 16) ? (arow0 + kk * 64) : (aprev0 + (long)(kk - 16) * pm0);
    const bf16* a1s = (kk < 16) ? (arow1 + kk * 64) : (aprev1 + (long)(kk - 16) * 64);
    gl_lds16(a0s, sA + w * 512);
    gl_lds16(a1s, sA + 2048 + w * 512);
    const bf16* bs = brow + kk * 64;
#pragma unroll
    for (int j = 0; j < 6; j++)
      gl_lds16(bs + (long)j * 32 * 2048, sB + j * 2048 + w * 512);
  };

  f32x4 acc[4][3] = {};

  stage(sA0, sB0, 0);
  stage(sA1, sB1, 1);
  stage(sA2, sB2, 2);
  asm volatile("s_waitcnt vmcnt(16)" ::: "memory");  // step0 landed
  BARRIER;

#pragma unroll 1
  for (int t = 0; t < 32; t++) {
    bf16x8 af[4][2], bfr[3][2];
#pragma unroll
    for (int i = 0; i < 4; i++) {
      int ra = i * 16 + lr;
#pragma unroll
      for (int ks = 0; ks < 2; ks++)
        af[i][ks] = *(const bf16x8*)&sA0[ra * 64 + (((ks * 4 + quad) ^ (ra & 7)) * 8)];
    }
#pragma unroll
    for (int n = 0; n < 3; n++) {
      int rb = w * 48 + n * 16 + lr;
#pragma unroll
      for (int ks = 0; ks < 2; ks++)
        bfr[n][ks] = *(const bf16x8*)&sB0[rb * 64 + (((ks * 4 + quad) ^ (rb & 7)) * 8)];
    }
    LGKM0;
    __builtin_amdgcn_s_setprio(1);
#pragma unroll
    for (int ks = 0; ks < 2; ks++)
#pragma unroll
      for (int i = 0; i < 4; i++)
#pragma unroll
        for (int n = 0; n < 3; n++)
          acc[i][n] = __builtin_amdgcn_mfma_f32_16x16x32_bf16(af[i][ks], bfr[n][ks],
                                                              acc[i][n], 0, 0, 0);
    __builtin_amdgcn_s_setprio(0);
    BARRIER;                       // all waves' reads of buf t%3 confirmed
    if (t + 3 < 32) {
      stage(sA0, sB0, t + 3);      // (t+3)%3 == t%3: reuse just-freed buffer
      asm volatile("s_waitcnt vmcnt(16)" ::: "memory");  // t+1 landed
    } else if (t == 29) {
      asm volatile("s_waitcnt vmcnt(8)" ::: "memory");
    } else if (t == 30) {
      asm volatile("s_waitcnt vmcnt(0)" ::: "memory");
    }
    BARRIER;
    bf16* tmpA = sA0; sA0 = sA1; sA1 = sA2; sA2 = tmpA;
    bf16* tmpB = sB0; sB0 = sB1; sB1 = sB2; sB2 = tmpB;
  }

  // epilogue: tanh -> Lt1 (w|a cols) / t1g (g cols)
#pragma unroll
  for (int i = 0; i < 4; i++)
#pragma unroll
    for (int n = 0; n < 3; n++) {
      int col = w * 48 + n * 16 + lr;
#pragma unroll
      for (int rg = 0; rg < 4; rg++) {
        int row = i * 16 + quad * 4 + rg;
        float tv = tanhf(acc[i][n][rg]);
        if (col < 128) Lt1[row * 136 + col] = (bf16)tv;
        else t1g[(long)(m0 + row) * 64 + (col - 128)] = (bf16)tv;
      }
    }
  __syncthreads();
#pragma unroll
  for (int rep = 0; rep < 4; rep++) {
    int idx = rep * 256 + tid;
    int row = idx >> 4, h = idx & 15;
    const bf16* rw = &Lt1[row * 136];
    const bf16* ra = rw + 64;
    const bf16* ww = w2T + h * 64;
    const bf16* aw = a2T + h * 64;
    float dw = 0.f, da = 0.f;
#pragma unroll
    for (int k = 0; k < 64; k++) {
      dw += (float)rw[k] * (float)ww[k];
      da += (float)ra[k] * (float)aw[k];
    }
    w_arr[h * TBTOK + m0 + row] = 0.60653066f * sigmf(w0[h] + dw);
    a_arr[h * TBTOK + m0 + row] = sigmf(a0[h] + da);
  }
}

// ---------------- scan1: fused prep + local 32-token scan; chunk-final -> Lend ------
// wave per (bh, chunk). 128 bh * 64 chunks = 8192 waves.
__global__ __launch_bounds__(256) void scan1_kern(
    const bf16* __restrict__ k_buf, const bf16* __restrict__ v_buf, const bf16* __restrict__ r_buf,
    const float* __restrict__ k_k, const float* __restrict__ r_k,
    const float* __restrict__ a_arr, const float* __restrict__ w_arr,
    float* __restrict__ kv2, float* __restrict__ Parr, float* __restrict__ bonus,
    float* __restrict__ Lend) {
  int wid = blockIdx.x * 4 + (threadIdx.x >> 6);
  int lane = threadIdx.x & 63;
  int bh = wid >> 6, c = wid & 63;
  int b = bh >> 4, h = bh & 15;
  int mstart = b * TSEQ + c * CHUNK;
  int kc = h * 64 + lane;
  float kkc = k_k[kc], rkc = r_k[kc];
  float st = 0.f, cw = 1.f;
  long mbase = (long)mstart * CDIM + kc;
  int hm = h * TBTOK + mstart;
  long sbase = ((long)hm) * 64 + lane;
  float kf = (float)k_buf[mbase] * kkc;
  float vf = (float)v_buf[mbase];
  float rf = (float)r_buf[mbase];
  float af = a_arr[hm];
  float wt = w_arr[hm];
  for (int t = 0; t < CHUNK; t++) {
    float kf_n = 0.f, vf_n = 0.f, rf_n = 0.f, af_n = 0.f, wt_n = 0.f;
    if (t < CHUNK - 1) {
      kf_n = (float)k_buf[mbase + CDIM] * kkc;
      vf_n = (float)v_buf[mbase + CDIM];
      rf_n = (float)r_buf[mbase + CDIM];
      af_n = a_arr[hm + 1];
      wt_n = w_arr[hm + 1];
    }
    float ss = wredsum(kf * kf);
    float kkn = kf / fmaxf(sqrtf(ss), 1e-12f);
    st = st * wt + kkn * vf * af;
    kv2[sbase] = st;
    cw *= wt;
    float bs = wredsum(rf * kkn * rkc);
    if (lane == 0) {
      Parr[hm] = cw;
      bonus[(mstart + t) * HN + h] = bs;
    }
    kf = kf_n; vf = vf_n; rf = rf_n; af = af_n; wt = wt_n;
    mbase += CDIM; hm += 1; sbase += 64;
  }
  // carry entering next chunk == this chunk's final state (P_chunk <= e^-16)
  Lend[(long)wid * 64 + lane] = st;
}

// ---------------- gate_post: g=sigmoid(t1g@g2) -> LDS; vectorized fixup+groupnorm ----
__global__ __launch_bounds__(256) void gate_post_kern(
    const bf16* __restrict__ t1g, const bf16* __restrict__ g2T,
    const float* __restrict__ kv2, const float* __restrict__ Parr,
    const float* __restrict__ Lend, const float* __restrict__ bonus,
    bf16* __restrict__ r_buf, const bf16* __restrict__ v_buf,
    const float* __restrict__ ln_w, const float* __restrict__ ln_b) {
  int ncol0 = blockIdx.x * 128;
  int m0 = blockIdx.y * 128;

  __shared__ bf16 Al[128 * 32];       // 8 KB
  __shared__ bf16 Bl[128 * 32];       // 8 KB
  __shared__ bf16 gtile[128 * 136];   // 34 KB

  int tid = threadIdx.x;
  int w = tid >> 6, lane = tid & 63, quad = lane >> 4, lr = lane & 15;
  int wm = (w & 1) * 64, wn = (w >> 1) * 64;

  f32x4 acc[4][4] = {};

  int r0 = tid >> 2, kc0 = (tid & 3) * 8;
  const bf16* ag0 = t1g + (long)(m0 + r0) * 64 + kc0;
  const bf16* ag1 = ag0 + (long)64 * 64;
  const bf16* bg0 = g2T + (long)(ncol0 + r0) * 64 + kc0;
  const bf16* bg1 = bg0 + (long)64 * 64;
  bf16* la0 = Al + w * 512;
  bf16* la1 = Al + 2048 + w * 512;
  bf16* lb0 = Bl + w * 512;
  bf16* lb1 = Bl + 2048 + w * 512;

  for (int k0 = 0; k0 < 64; k0 += 32) {
    gl_lds16(ag0, la0);
    gl_lds16(ag1, la1);
    gl_lds16(bg0, lb0);
    gl_lds16(bg1, lb1);
    ag0 += 32; ag1 += 32; bg0 += 32; bg1 += 32;
    __syncthreads();
    bf16x8 af[4], bff[4];
#pragma unroll
    for (int i = 0; i < 4; i++) af[i] = *(const bf16x8*)&Al[(wm + i * 16 + lr) * 32 + quad * 8];
#pragma unroll
    for (int j = 0; j < 4; j++) bff[j] = *(const bf16x8*)&Bl[(wn + j * 16 + lr) * 32 + quad * 8];
#pragma unroll
    for (int i = 0; i < 4; i++)
#pragma unroll
      for (int j = 0; j < 4; j++)
        acc[i][j] = __builtin_amdgcn_mfma_f32_16x16x32_bf16(af[i], bff[j], acc[i][j], 0, 0, 0);
    __syncthreads();
  }
  // phase 1b: sigmoid(gate) -> LDS tile in C-layout
#pragma unroll
  for (int i = 0; i < 4; i++)
#pragma unroll
    for (int j = 0; j < 4; j++)
#pragma unroll
      for (int rg = 0; rg < 4; rg++) {
        int row = wm + i * 16 + quad * 4 + rg;
        int col = wn + j * 16 + lr;
        gtile[row * 136 + col] = (bf16)sigmf(acc[i][j][rg]);
      }
  __syncthreads();

  // phase 2: 8 contiguous channels per thread; fully vectorized global access
  int c_loc = (tid & 15) * 8;            // 0..120
  int col_g = ncol0 + c_loc;
  int h = col_g >> 6;
  int d0 = col_g & 63;
  f32x4 lnw0 = *(const f32x4*)(ln_w + col_g);
  f32x4 lnw1 = *(const f32x4*)(ln_w + col_g + 4);
  f32x4 lnb0 = *(const f32x4*)(ln_b + col_g);
  f32x4 lnb1 = *(const f32x4*)(ln_b + col_g + 4);
#pragma unroll
  for (int jj = 0; jj < 8; jj++) {
    int row = jj * 16 + (tid >> 4);
    int row_g = m0 + row;
    int b = row_g >> 11;
    int ch = (row_g & (TSEQ - 1)) >> 5;
    long kvb = ((long)h * TBTOK + row_g) * 64 + d0;
    f32x4 st0 = *(const f32x4*)(kv2 + kvb);
    f32x4 st1 = *(const f32x4*)(kv2 + kvb + 4);
    f32x4 cy0 = {0.f, 0.f, 0.f, 0.f}, cy1 = {0.f, 0.f, 0.f, 0.f};
    if (ch != 0) {
      long lb = ((long)((b * 16 + h) * NCH + ch - 1)) * 64 + d0;
      cy0 = *(const f32x4*)(Lend + lb);
      cy1 = *(const f32x4*)(Lend + lb + 4);
    }
    float pw = Parr[h * TBTOK + row_g];
    float bs = bonus[row_g * HN + h];
    long rb = (long)row_g * CDIM + col_g;
    bf16x8 rf8 = *(const bf16x8*)(r_buf + rb);
    bf16x8 vf8 = *(const bf16x8*)(v_buf + rb);
    bf16x8 g8 = *(const bf16x8*)&gtile[row * 136 + c_loc];
    float xw[8];
#pragma unroll
    for (int q = 0; q < 4; q++) {
      xw[q]     = (st0[q] + pw * cy0[q]) * (float)rf8[q]     + bs * (float)vf8[q];
      xw[4 + q] = (st1[q] + pw * cy1[q]) * (float)rf8[4 + q] + bs * (float)vf8[4 + q];
    }
    float sum = 0.f;
#pragma unroll
    for (int q = 0; q < 8; q++) sum += xw[q];
    float mn = redsum8(sum) * (1.f / 64.f);
    float vs = 0.f;
#pragma unroll
    for (int q = 0; q < 8; q++) {
      xw[q] -= mn;
      vs += xw[q] * xw[q];
    }
    float var = redsum8(vs) * (1.f / 64.f);
    float rq = rsqrtf(var + 1e-5f);
    bf16x8 o8;
#pragma unroll
    for (int q = 0; q < 4; q++) {
      o8[q]     = (bf16)((xw[q] * rq * lnw0[q] + lnb0[q]) * (float)g8[q]);
      o8[4 + q] = (bf16)((xw[4 + q] * rq * lnw1[q] + lnb1[q]) * (float)g8[4 + q]);
    }
    *(bf16x8*)(r_buf + rb) = o8;
  }
}

extern "C" void kernel_launch(void* const* d_in, const int* in_sizes, int n_in,
                              void* d_out, int out_size, void* d_ws, size_t ws_size,
                              hipStream_t stream) {
  const float* x    = (const float*)d_in[0];
  const float* x_r  = (const float*)d_in[1];
  const float* x_w  = (const float*)d_in[2];
  const float* x_k  = (const float*)d_in[3];
  const float* x_v  = (const float*)d_in[4];
  const float* x_a  = (const float*)d_in[5];
  const float* x_g  = (const float*)d_in[6];
  const float* w0   = (const float*)d_in[7];
  const float* w1   = (const float*)d_in[8];
  const float* w2   = (const float*)d_in[9];
  const float* a0   = (const float*)d_in[10];
  const float* a1   = (const float*)d_in[11];
  const float* a2   = (const float*)d_in[12];
  // v0,v1,v2 (13,14,15) unused: v_res_gate is a no-op in the reference
  const float* g1   = (const float*)d_in[16];
  const float* g2   = (const float*)d_in[17];
  const float* k_k  = (const float*)d_in[18];
  const float* r_k  = (const float*)d_in[19];
  const float* Wr   = (const float*)d_in[20];
  const float* Wk   = (const float*)d_in[21];
  const float* Wv   = (const float*)d_in[22];
  const float* Wo   = (const float*)d_in[23];
  const float* ln_w = (const float*)d_in[24];
  const float* ln_b = (const float*)d_in[25];
  float* out = (float*)d_out;

  char* p = (char*)d_ws;
  auto carve = [&](size_t bytes) {
    void* r = (void*)p;
    p += (bytes + 255) & ~(size_t)255;
    return r;
  };
  bf16* WrT = (bf16*)carve(1024 * 1024 * 2);
  bf16* WkT = (bf16*)carve(1024 * 1024 * 2);
  bf16* WvT = (bf16*)carve(1024 * 1024 * 2);
  bf16* WoT = (bf16*)carve(1024 * 1024 * 2);
  bf16* Bcat = (bf16*)carve(192 * 2048 * 2);
  bf16* g2T  = (bf16*)carve(1024 * 64 * 2);
  bf16* w2T  = (bf16*)carve(16 * 64 * 2);
  bf16* a2T  = (bf16*)carve(16 * 64 * 2);
  float* zpad = (float*)carve(64 * 4);
  bf16* t1g   = (bf16*)carve((size_t)TBTOK * 64 * 2);
  bf16* r_buf = (bf16*)carve((size_t)TBTOK * CDIM * 2);
  bf16* k_buf = (bf16*)carve((size_t)TBTOK * CDIM * 2);
  bf16* v_buf = (bf16*)carve((size_t)TBTOK * CDIM * 2);
  float* w_arr = (float*)carve((size_t)TBTOK * HN * 4);
  float* a_arr = (float*)carve((size_t)TBTOK * HN * 4);
  float* bonus = (float*)carve((size_t)TBTOK * HN * 4);
  float* Parr  = (float*)carve((size_t)TBTOK * HN * 4);
  float* Lend  = (float*)carve((size_t)128 * NCH * 64 * 4);
  bf16* xr  = (bf16*)carve((size_t)TBTOK * CDIM * 2);
  bf16* xk  = (bf16*)carve((size_t)TBTOK * CDIM * 2);
  bf16* xv  = (bf16*)carve((size_t)TBTOK * CDIM * 2);
  bf16* xbf = (bf16*)carve((size_t)TBTOK * CDIM * 2);
  float* kv2 = (float*)xv;  // 64MB = xv+xbf, dead before scan1

  // 1. mixcvt + all weight prep
  prep_kern<<<dim3(8192 + 4545), 256, 0, stream>>>(
      x, x_r, x_k, x_v, xr, xk, xv, xbf,
      Wr, Wk, Wv, Wo, w1, a1, g1, x_w, x_a, x_g, g2, w2, a2,
      WrT, WkT, WvT, WoT, Bcat, g2T, w2T, a2T, zpad);
  // 2. LoRA stage1 (merged 192-col GEMM + fused stage2 dots)
  stage1_kern<<<dim3(TBTOK / 64), 256, 0, stream>>>(
      xbf, Bcat, zpad, w2T, a2T, w0, a0, t1g, w_arr, a_arr);
  // 3. r,k,v projections: 768 blocks, XCD-local n-fastest decode.
  gemm256_kern<bf16><<<dim3(768), 512, 0, stream>>>(
      xr, xk, xv, WrT, WkT, WvT, r_buf, k_buf, v_buf, 1024);
  // 4. WKV local scans (CHUNK=32; carry == prev chunk-final state)
  scan1_kern<<<dim3(128 * NCH / 4), 256, 0, stream>>>(
      k_buf, v_buf, r_buf, k_k, r_k, a_arr, w_arr, kv2, Parr, bonus, Lend);
  // 5. gate GEMM + vectorized fixup/groupnorm/gating -> an (into r_buf)
  gate_post_kern<<<dim3(8, TBTOK / 128), 256, 0, stream>>>(
      t1g, g2T, kv2, Parr, Lend, bonus, r_buf, v_buf, ln_w, ln_b);
  // 6. out = an @ Wo  (f32 output)
  gemm256_kern<float><<<dim3(256), 512, 0, stream>>>(
      r_buf, r_buf, r_buf, WoT, WoT, WoT, out, out, out, 1024);
}

// Round 10
// 505.039 us; speedup vs baseline: 1.0297x; 1.0230x over previous
//
#include <hip/hip_runtime.h>

// RWKV v7 TimeMix forward, MI355X gfx950.
// B=8 T=2048 C=1024 H=16 D=64 DLOW=64. I/O f32, internal bf16 MFMA + f32 scan.
// R16: gemm256 reverted to R13 exact (best measured: 121us, 0 bank conflicts;
//      R15's 32x32 MFMA had inherent 4-way LDS conflicts, 9.4M counted).
//      stage1: 2-deep pipeline + Lt1 aliased into Bbuf -> LDS 113->64KB ->
//      2 blocks/CU (2 waves/SIMD, was 1) for latency hiding. 6 launches.

typedef __bf16 bf16;
typedef __attribute__((ext_vector_type(8))) __bf16 bf16x8;
typedef __attribute__((ext_vector_type(4))) float f32x4;

#define TBTOK 16384   // B*T
#define TSEQ  2048
#define CDIM  1024
#define HN    16
#define CHUNK 32
#define NCH   64      // TSEQ / CHUNK

__device__ __forceinline__ float wredsum(float v) {
#pragma unroll
  for (int o = 32; o > 0; o >>= 1) v += __shfl_xor(v, o, 64);
  return v;
}
__device__ __forceinline__ float redsum8(float v) {  // 8 consecutive lanes
#pragma unroll
  for (int o = 4; o > 0; o >>= 1) v += __shfl_xor(v, o, 64);
  return v;
}
__device__ __forceinline__ float sigmf(float x) { return 1.f / (1.f + expf(-x)); }

// async global->LDS, 16 bytes/lane. LDS base wave-uniform (HW adds lane*16).
__device__ __forceinline__ void gl_lds16(const bf16* g, bf16* l) {
  __builtin_amdgcn_global_load_lds(
      (const __attribute__((address_space(1))) unsigned int*)g,
      (__attribute__((address_space(3))) unsigned int*)l, 16, 0, 0);
}

// ---------------- prep: mixcvt (blocks 0..8191) + all weight transposes ----------
__global__ __launch_bounds__(256) void prep_kern(
    const float* __restrict__ x, const float* __restrict__ mr,
    const float* __restrict__ mk, const float* __restrict__ mv,
    bf16* __restrict__ xr, bf16* __restrict__ xk, bf16* __restrict__ xv,
    bf16* __restrict__ xbf,
    const float* __restrict__ Wr, const float* __restrict__ Wk,
    const float* __restrict__ Wv, const float* __restrict__ Wo,
    const float* __restrict__ w1, const float* __restrict__ a1, const float* __restrict__ g1,
    const float* __restrict__ mw, const float* __restrict__ ma, const float* __restrict__ mg,
    const float* __restrict__ g2, const float* __restrict__ w2, const float* __restrict__ a2,
    bf16* __restrict__ WrT, bf16* __restrict__ WkT, bf16* __restrict__ WvT, bf16* __restrict__ WoT,
    bf16* __restrict__ Bcat, bf16* __restrict__ g2T,
    bf16* __restrict__ w2T, bf16* __restrict__ a2T, float* __restrict__ zpad) {
  int bid0 = blockIdx.x;
  int tid = threadIdx.x;
  if (bid0 < 8192) {
    long i8 = ((long)bid0 * 256 + tid) * 8;
    int m = (int)(i8 >> 10);
    int c = (int)(i8 & 1023);
    f32x4 x0 = *(const f32x4*)(x + i8);
    f32x4 x1 = *(const f32x4*)(x + i8 + 4);
    f32x4 p0 = {0.f, 0.f, 0.f, 0.f}, p1 = {0.f, 0.f, 0.f, 0.f};
    if ((m & (TSEQ - 1)) != 0) {
      p0 = *(const f32x4*)(x + i8 - CDIM);
      p1 = *(const f32x4*)(x + i8 - CDIM + 4);
    }
    f32x4 r0 = *(const f32x4*)(mr + c), r1 = *(const f32x4*)(mr + c + 4);
    f32x4 k0 = *(const f32x4*)(mk + c), k1 = *(const f32x4*)(mk + c + 4);
    f32x4 v0 = *(const f32x4*)(mv + c), v1 = *(const f32x4*)(mv + c + 4);
    bf16x8 or_, ok_, ov_, ox_;
#pragma unroll
    for (int j = 0; j < 4; j++) {
      float s0 = x0[j] - p0[j], s1 = x1[j] - p1[j];
      or_[j] = (bf16)(x0[j] + s0 * r0[j]); or_[4 + j] = (bf16)(x1[j] + s1 * r1[j]);
      ok_[j] = (bf16)(x0[j] + s0 * k0[j]); ok_[4 + j] = (bf16)(x1[j] + s1 * k1[j]);
      ov_[j] = (bf16)(x0[j] + s0 * v0[j]); ov_[4 + j] = (bf16)(x1[j] + s1 * v1[j]);
      ox_[j] = (bf16)x0[j];                ox_[4 + j] = (bf16)x1[j];
    }
    *(bf16x8*)(xr + i8) = or_;
    *(bf16x8*)(xk + i8) = ok_;
    *(bf16x8*)(xv + i8) = ov_;
    *(bf16x8*)(xbf + i8) = ox_;
    return;
  }
  int bid = bid0 - 8192;
  int tx = tid & 31, ty = tid >> 5;  // 32 x 8
  __shared__ bf16 tile[32][33];
  if (bid < 4096) {
    int sel = bid >> 10, t = bid & 1023;
    int k0 = (t >> 5) * 32, n0 = (t & 31) * 32;
    const float* src = sel == 0 ? Wr : (sel == 1 ? Wk : (sel == 2 ? Wv : Wo));
    bf16* dst = sel == 0 ? WrT : (sel == 1 ? WkT : (sel == 2 ? WvT : WoT));
#pragma unroll
    for (int i = 0; i < 4; i++)
      tile[ty + i * 8][tx] = (bf16)src[(long)(k0 + ty + i * 8) * 1024 + n0 + tx];
    __syncthreads();
#pragma unroll
    for (int i = 0; i < 4; i++)
      dst[(long)(n0 + ty + i * 8) * 1024 + k0 + tx] = tile[tx][ty + i * 8];
  } else if (bid < 4480) {
    int idx = bid - 4096;
    int mat = idx >> 7, rem = idx & 127;
    int half = rem >> 6, t = rem & 63;
    int k0 = (t >> 1) * 32, n0 = (t & 1) * 32;
    const float* W = mat == 0 ? w1 : (mat == 1 ? a1 : g1);
    const float* mx = mat == 0 ? mw : (mat == 1 ? ma : mg);
#pragma unroll
    for (int i = 0; i < 4; i++) {
      int k = k0 + ty + i * 8;
      float s = half == 0 ? (1.f + mx[k]) : (-mx[k]);
      tile[ty + i * 8][tx] = (bf16)(s * W[(long)k * 64 + n0 + tx]);
    }
    __syncthreads();
#pragma unroll
    for (int i = 0; i < 4; i++)
      Bcat[(long)(mat * 64 + n0 + ty + i * 8) * 2048 + half * 1024 + k0 + tx] =
          tile[tx][ty + i * 8];
  } else if (bid < 4544) {
    int t = bid - 4480;
    int k0 = (t >> 5) * 32, n0 = (t & 31) * 32;
#pragma unroll
    for (int i = 0; i < 4; i++)
      tile[ty + i * 8][tx] = (bf16)g2[(long)(k0 + ty + i * 8) * 1024 + n0 + tx];
    __syncthreads();
#pragma unroll
    for (int i = 0; i < 4; i++)
      g2T[(long)(n0 + ty + i * 8) * 64 + k0 + tx] = tile[tx][ty + i * 8];
  } else {
#pragma unroll
    for (int rep = 0; rep < 4; rep++) {
      int idx = rep * 256 + tid;  // 0..1023
      int k = idx >> 4, h = idx & 15;
      w2T[h * 64 + k] = (bf16)w2[idx];
      a2T[h * 64 + k] = (bf16)a2[idx];
    }
    if (tid < 64) zpad[tid] = 0.f;
  }
}

// ---------------- big GEMM: 256x256, BK=64, 8 waves, single-barrier phases -----
// (R13 exact.) LDS: A/B half-tiles [2 dbuf][2 half][128x64] = 128 KiB. Per
// K-tile pair: 8 single-barrier phases, 16 MFMA each; stage B at P2/P6, A at
// P3/P7; vmcnt(8) => prior tile landed. XCD-local n-fastest decode.
#define BARRIER __builtin_amdgcn_s_barrier()
#define LGKM0                                              \
  do {                                                     \
    asm volatile("s_waitcnt lgkmcnt(0)" ::: "memory");     \
    __builtin_amdgcn_sched_barrier(0);                     \
  } while (0)

#define READ_A(HALFP, QM)                                                                \
  {                                                                                      \
    const bf16* _h = (HALFP);                                                            \
    _Pragma("unroll") for (int i = 0; i < 4; i++) {                                      \
      int ra = (QM)*64 + i * 16 + lr;                                                    \
      _Pragma("unroll") for (int ks = 0; ks < 2; ks++)                                   \
          af[i][ks] = *(const bf16x8*)&_h[ra * 64 + (((ks * 4 + quad) ^ (ra & 7)) * 8)]; \
    }                                                                                    \
  }

#define READ_B(HALFP, QN)                                                                \
  {                                                                                      \
    const bf16* _h = (HALFP);                                                            \
    _Pragma("unroll") for (int jj = 0; jj < 2; jj++) {                                   \
      int rb = bro + ((QN)*2 + jj) * 16 + lr;                                            \
      _Pragma("unroll") for (int ks = 0; ks < 2; ks++)                                   \
          bfr[(QN)*2 + jj][ks] =                                                         \
              *(const bf16x8*)&_h[rb * 64 + (((ks * 4 + quad) ^ (rb & 7)) * 8)];         \
    }                                                                                    \
  }

#define MFMA16(QM, QN)                                                            \
  __builtin_amdgcn_s_setprio(1);                                                  \
  _Pragma("unroll") for (int ks = 0; ks < 2; ks++)                                \
  _Pragma("unroll") for (int i = 0; i < 4; i++)                                   \
  _Pragma("unroll") for (int jj = 0; jj < 2; jj++)                                \
      acc[(QM)*4 + i][(QN)*2 + jj] = __builtin_amdgcn_mfma_f32_16x16x32_bf16(     \
          af[i][ks], bfr[(QN)*2 + jj][ks], acc[(QM)*4 + i][(QN)*2 + jj], 0, 0, 0);\
  __builtin_amdgcn_s_setprio(0);

template <typename OT>
__global__ __launch_bounds__(512, 2) void gemm256_kern(
    const bf16* __restrict__ A0, const bf16* __restrict__ A1, const bf16* __restrict__ A2,
    const bf16* __restrict__ BT0, const bf16* __restrict__ BT1, const bf16* __restrict__ BT2,
    OT* __restrict__ out0, OT* __restrict__ out1, OT* __restrict__ out2,
    int K) {
  int nwg = gridDim.x;            // multiple of 8 (768 rkv / 256 Wo)
  int id = blockIdx.x;
  int qq = nwg >> 3;
  int wg = (id & 7) * qq + (id >> 3);   // bijective XCD swizzle (contiguous chunk)
  int mat = wg >> 8;              // 256 blocks per mat
  int rem = wg & 255;
  int m0 = (rem >> 2) << 8;       // n fastest: 4 n-tiles of an m-panel adjacent
  int n0 = (rem & 3) << 8;
  const bf16* Am = mat == 0 ? A0 : (mat == 1 ? A1 : A2);
  const bf16* BTm = mat == 0 ? BT0 : (mat == 1 ? BT1 : BT2);
  OT* out = mat == 0 ? out0 : (mat == 1 ? out1 : out2);

  __shared__ bf16 Al[2][2][128 * 64];   // [dbuf][half] 64 KB
  __shared__ bf16 Bl[2][2][128 * 64];   // 64 KB

  int tid = threadIdx.x;
  int w = tid >> 6, lane = tid & 63, quad = lane >> 4, lr = lane & 15;
  int wr = w >> 2, wc = w & 3;       // 2M x 4N waves; per-wave out = 128x64
  int hb = wc >> 1, bro = (wc & 1) * 64;

  // staging: per thread covers rows (tid>>3), (tid>>3)+64 of a half-tile;
  // global column chunk pre-swizzled so linear LDS dest + swizzled read match.
  int swz = ((tid & 7) ^ ((tid >> 3) & 7)) * 8;
  const bf16* aBase = Am + (long)(m0 + (tid >> 3)) * K + swz;
  const bf16* bBase = BTm + (long)(n0 + (tid >> 3)) * K + swz;

  auto stgA = [&](int db, int h, int t) {
    const bf16* g = aBase + (long)(h * 128) * K + t * 64;
    bf16* l = &Al[db][h][0] + w * 512;
    gl_lds16(g, l);
    gl_lds16(g + (long)64 * K, l + 4096);
  };
  auto stgB = [&](int db, int h, int t) {
    const bf16* g = bBase + (long)(h * 128) * K + t * 64;
    bf16* l = &Bl[db][h][0] + w * 512;
    gl_lds16(g, l);
    gl_lds16(g + (long)64 * K, l + 4096);
  };

  const bf16* A0p = &Al[0][wr][0];
  const bf16* A1p = &Al[1][wr][0];
  const bf16* B0p = &Bl[0][hb][0];
  const bf16* B1p = &Bl[1][hb][0];

  f32x4 acc[8][4] = {};
  bf16x8 af[4][2], bfr[4][2];

  int NT = K >> 6, NU = NT >> 1;

  // prologue: tile0 (B,B,A,A) then tile1 (B,B,A,A); wait tile0, keep tile1 in flight
  stgB(0, 0, 0); stgB(0, 1, 0); stgA(0, 0, 0); stgA(0, 1, 0);
  stgB(1, 0, 1); stgB(1, 1, 1); stgA(1, 0, 1); stgA(1, 1, 1);
  asm volatile("s_waitcnt vmcnt(8)" ::: "memory");
  BARRIER;

#pragma unroll 1
  for (int u = 0; u < NU; u++) {
    int t2 = 2 * u + 2, t3 = 2 * u + 3;
    // ---- P0: tile t0 quad (0,0) ----
    READ_A(A0p, 0);
    READ_B(B0p, 0);
    LGKM0;
    MFMA16(0, 0);
    BARRIER;
    // ---- P1: quad (0,1) ----
    READ_B(B0p, 1);
    LGKM0;
    MFMA16(0, 1);
    BARRIER;
    // ---- P2: quad (1,1); stage B(t2) (dbuf0-B last read P1, barrier passed) ----
    READ_A(A0p, 1);
    if (t2 < NT) { stgB(0, 0, t2); stgB(0, 1, t2); }
    LGKM0;
    MFMA16(1, 1);
    BARRIER;
    // ---- P3: stage A(t2) (dbuf0-A last read P2); MFMA on P2/P0 regs;
    //      vmcnt(8): 8 just-issued t2 loads outstanding => t1 landed ----
    if (t2 < NT) { stgA(0, 0, t2); stgA(0, 1, t2); }
    __builtin_amdgcn_sched_barrier(0);
    MFMA16(1, 0);
    if (t2 < NT) { asm volatile("s_waitcnt vmcnt(8)" ::: "memory"); }
    else         { asm volatile("s_waitcnt vmcnt(0)" ::: "memory"); }
    BARRIER;
    // ---- P4: tile t1 quad (0,0) ----
    READ_A(A1p, 0);
    READ_B(B1p, 0);
    LGKM0;
    MFMA16(0, 0);
    BARRIER;
    // ---- P5: quad (0,1) ----
    READ_B(B1p, 1);
    LGKM0;
    MFMA16(0, 1);
    BARRIER;
    // ---- P6: quad (1,1); stage B(t3) ----
    READ_A(A1p, 1);
    if (t3 < NT) { stgB(1, 0, t3); stgB(1, 1, t3); }
    LGKM0;
    MFMA16(1, 1);
    BARRIER;
    // ---- P7: stage A(t3); vmcnt(8) => t2 landed ----
    if (t3 < NT) { stgA(1, 0, t3); stgA(1, 1, t3); }
    __builtin_amdgcn_sched_barrier(0);
    MFMA16(1, 0);
    if (t3 < NT) { asm volatile("s_waitcnt vmcnt(8)" ::: "memory"); }
    else         { asm volatile("s_waitcnt vmcnt(0)" ::: "memory"); }
    BARRIER;
  }

#pragma unroll
  for (int i = 0; i < 8; i++)
#pragma unroll
    for (int j = 0; j < 4; j++)
#pragma unroll
      for (int rg = 0; rg < 4; rg++) {
        int row = m0 + wr * 128 + i * 16 + quad * 4 + rg;
        int col = n0 + wc * 64 + j * 16 + lr;
        out[(long)row * CDIM + col] = (OT)acc[i][j][rg];
      }
}

// ---------------- stage1: [x|xprev]@Bcat^T (192 cols), BK=64, 2-buffer pipeline ----
// 256 blocks x 256 thr (4 waves; wave w owns cols 48w..48w+47). K=2048 = 32 steps.
// 2-deep pipeline, vmcnt(8)-counted; Lt1 aliased into Bbuf[0] (dead after loop).
// LDS = 16 + 48 = 64 KB -> 2 blocks/CU = 2 waves/SIMD (was 1: 113 KB).
__global__ __launch_bounds__(256) void stage1_kern(
    const bf16* __restrict__ xbf, const bf16* __restrict__ Bcat,
    const float* __restrict__ zpad, const bf16* __restrict__ w2T, const bf16* __restrict__ a2T,
    const float* __restrict__ w0, const float* __restrict__ a0,
    bf16* __restrict__ t1g, float* __restrict__ w_arr, float* __restrict__ a_arr) {
  int m0 = blockIdx.x * 64;
  __shared__ bf16 Abuf[2][64 * 64];    // 16 KB
  __shared__ bf16 Bbuf[2][192 * 64];   // 48 KB
  bf16* Lt1 = &Bbuf[0][0];             // alias: Bbuf dead after K-loop (17KB<24KB)

  int tid = threadIdx.x;
  int w = tid >> 6, lane = tid & 63, quad = lane >> 4, lr = lane & 15;

  // staging maps: A units = 64 rows x 8 slots; thread covers units tid, tid+256.
  int r0 = tid >> 3, s0 = tid & 7;
  int c0 = (s0 ^ (r0 & 7)) * 8;              // pre-swizzled column chunk
  const bf16* arow0 = xbf + (long)(m0 + r0) * CDIM + c0;
  const bf16* arow1 = xbf + (long)(m0 + 32 + r0) * CDIM + c0;
  bool fr0 = ((m0 + r0) & (TSEQ - 1)) == 0;  // true only for r0==0 at seq starts
  const bf16* aprev0 = fr0 ? ((const bf16*)zpad) : (arow0 - CDIM);
  const bf16* aprev1 = arow1 - CDIM;         // rows 32..63 never first-of-seq
  long pm0 = fr0 ? 0 : 64;
  // B units = 192 rows x 8 slots; thread covers units tid + j*256 (rows r0+32j)
  const bf16* brow = Bcat + (long)r0 * 2048 + c0;

  bf16* sA0 = &Abuf[0][0]; bf16* sA1 = &Abuf[1][0];
  bf16* sB0 = &Bbuf[0][0]; bf16* sB1 = &Bbuf[1][0];

  auto stage = [&](bf16* sA, bf16* sB, int kk) {
    const bf16* a0s = (kk < 16) ? (arow0 + kk * 64) : (aprev0 + (long)(kk - 16) * pm0);
    const bf16* a1s = (kk < 16) ? (arow1 + kk * 64) : (aprev1 + (long)(kk - 16) * 64);
    gl_lds16(a0s, sA + w * 512);
    gl_lds16(a1s, sA + 2048 + w * 512);
    const bf16* bs = brow + kk * 64;
#pragma unroll
    for (int j = 0; j < 6; j++)
      gl_lds16(bs + (long)j * 32 * 2048, sB + j * 2048 + w * 512);
  };

  f32x4 acc[4][3] = {};

  stage(sA0, sB0, 0);
  stage(sA1, sB1, 1);
  asm volatile("s_waitcnt vmcnt(8)" ::: "memory");  // step0 landed (step1 in flight)
  BARRIER;

#pragma unroll 1
  for (int t = 0; t < 32; t++) {
    bf16x8 af[4][2], bfr[3][2];
#pragma unroll
    for (int i = 0; i < 4; i++) {
      int ra = i * 16 + lr;
#pragma unroll
      for (int ks = 0; ks < 2; ks++)
        af[i][ks] = *(const bf16x8*)&sA0[ra * 64 + (((ks * 4 + quad) ^ (ra & 7)) * 8)];
    }
#pragma unroll
    for (int n = 0; n < 3; n++) {
      int rb = w * 48 + n * 16 + lr;
#pragma unroll
      for (int ks = 0; ks < 2; ks++)
        bfr[n][ks] = *(const bf16x8*)&sB0[rb * 64 + (((ks * 4 + quad) ^ (rb & 7)) * 8)];
    }
    LGKM0;
    __builtin_amdgcn_s_setprio(1);
#pragma unroll
    for (int ks = 0; ks < 2; ks++)
#pragma unroll
      for (int i = 0; i < 4; i++)
#pragma unroll
        for (int n = 0; n < 3; n++)
          acc[i][n] = __builtin_amdgcn_mfma_f32_16x16x32_bf16(af[i][ks], bfr[n][ks],
                                                              acc[i][n], 0, 0, 0);
    __builtin_amdgcn_s_setprio(0);
    BARRIER;                       // all waves' reads of buf t%2 confirmed
    if (t + 2 < 32) {
      stage(sA0, sB0, t + 2);      // reuse just-freed buffer
      // 8 just-issued t+2 loads outstanding => t+1 (older) fully landed
      asm volatile("s_waitcnt vmcnt(8)" ::: "memory");
    } else {
      asm volatile("s_waitcnt vmcnt(0)" ::: "memory");
    }
    BARRIER;
    bf16* tmpA = sA0; sA0 = sA1; sA1 = tmpA;
    bf16* tmpB = sB0; sB0 = sB1; sB1 = tmpB;
  }

  // epilogue: tanh -> Lt1 (w|a cols, aliased into Bbuf) / t1g (g cols)
#pragma unroll
  for (int i = 0; i < 4; i++)
#pragma unroll
    for (int n = 0; n < 3; n++) {
      int col = w * 48 + n * 16 + lr;
#pragma unroll
      for (int rg = 0; rg < 4; rg++) {
        int row = i * 16 + quad * 4 + rg;
        float tv = tanhf(acc[i][n][rg]);
        if (col < 128) Lt1[row * 136 + col] = (bf16)tv;
        else t1g[(long)(m0 + row) * 64 + (col - 128)] = (bf16)tv;
      }
    }
  __syncthreads();
#pragma unroll
  for (int rep = 0; rep < 4; rep++) {
    int idx = rep * 256 + tid;
    int row = idx >> 4, h = idx & 15;
    const bf16* rw = &Lt1[row * 136];
    const bf16* ra = rw + 64;
    const bf16* ww = w2T + h * 64;
    const bf16* aw = a2T + h * 64;
    float dw = 0.f, da = 0.f;
#pragma unroll
    for (int k = 0; k < 64; k++) {
      dw += (float)rw[k] * (float)ww[k];
      da += (float)ra[k] * (float)aw[k];
    }
    w_arr[h * TBTOK + m0 + row] = 0.60653066f * sigmf(w0[h] + dw);
    a_arr[h * TBTOK + m0 + row] = sigmf(a0[h] + da);
  }
}

// ---------------- scan1: fused prep + local 32-token scan; chunk-final -> Lend ------
// wave per (bh, chunk). 128 bh * 64 chunks = 8192 waves.
__global__ __launch_bounds__(256) void scan1_kern(
    const bf16* __restrict__ k_buf, const bf16* __restrict__ v_buf, const bf16* __restrict__ r_buf,
    const float* __restrict__ k_k, const float* __restrict__ r_k,
    const float* __restrict__ a_arr, const float* __restrict__ w_arr,
    float* __restrict__ kv2, float* __restrict__ Parr, float* __restrict__ bonus,
    float* __restrict__ Lend) {
  int wid = blockIdx.x * 4 + (threadIdx.x >> 6);
  int lane = threadIdx.x & 63;
  int bh = wid >> 6, c = wid & 63;
  int b = bh >> 4, h = bh & 15;
  int mstart = b * TSEQ + c * CHUNK;
  int kc = h * 64 + lane;
  float kkc = k_k[kc], rkc = r_k[kc];
  float st = 0.f, cw = 1.f;
  long mbase = (long)mstart * CDIM + kc;
  int hm = h * TBTOK + mstart;
  long sbase = ((long)hm) * 64 + lane;
  float kf = (float)k_buf[mbase] * kkc;
  float vf = (float)v_buf[mbase];
  float rf = (float)r_buf[mbase];
  float af = a_arr[hm];
  float wt = w_arr[hm];
  for (int t = 0; t < CHUNK; t++) {
    float kf_n = 0.f, vf_n = 0.f, rf_n = 0.f, af_n = 0.f, wt_n = 0.f;
    if (t < CHUNK - 1) {
      kf_n = (float)k_buf[mbase + CDIM] * kkc;
      vf_n = (float)v_buf[mbase + CDIM];
      rf_n = (float)r_buf[mbase + CDIM];
      af_n = a_arr[hm + 1];
      wt_n = w_arr[hm + 1];
    }
    float ss = wredsum(kf * kf);
    float kkn = kf / fmaxf(sqrtf(ss), 1e-12f);
    st = st * wt + kkn * vf * af;
    kv2[sbase] = st;
    cw *= wt;
    float bs = wredsum(rf * kkn * rkc);
    if (lane == 0) {
      Parr[hm] = cw;
      bonus[(mstart + t) * HN + h] = bs;
    }
    kf = kf_n; vf = vf_n; rf = rf_n; af = af_n; wt = wt_n;
    mbase += CDIM; hm += 1; sbase += 64;
  }
  // carry entering next chunk == this chunk's final state (P_chunk <= e^-16)
  Lend[(long)wid * 64 + lane] = st;
}

// ---------------- gate_post: g=sigmoid(t1g@g2) -> LDS; vectorized fixup+groupnorm ----
__global__ __launch_bounds__(256) void gate_post_kern(
    const bf16* __restrict__ t1g, const bf16* __restrict__ g2T,
    const float* __restrict__ kv2, const float* __restrict__ Parr,
    const float* __restrict__ Lend, const float* __restrict__ bonus,
    bf16* __restrict__ r_buf, const bf16* __restrict__ v_buf,
    const float* __restrict__ ln_w, const float* __restrict__ ln_b) {
  int ncol0 = blockIdx.x * 128;
  int m0 = blockIdx.y * 128;

  __shared__ bf16 Al[128 * 32];       // 8 KB
  __shared__ bf16 Bl[128 * 32];       // 8 KB
  __shared__ bf16 gtile[128 * 136];   // 34 KB

  int tid = threadIdx.x;
  int w = tid >> 6, lane = tid & 63, quad = lane >> 4, lr = lane & 15;
  int wm = (w & 1) * 64, wn = (w >> 1) * 64;

  f32x4 acc[4][4] = {};

  int r0 = tid >> 2, kc0 = (tid & 3) * 8;
  const bf16* ag0 = t1g + (long)(m0 + r0) * 64 + kc0;
  const bf16* ag1 = ag0 + (long)64 * 64;
  const bf16* bg0 = g2T + (long)(ncol0 + r0) * 64 + kc0;
  const bf16* bg1 = bg0 + (long)64 * 64;
  bf16* la0 = Al + w * 512;
  bf16* la1 = Al + 2048 + w * 512;
  bf16* lb0 = Bl + w * 512;
  bf16* lb1 = Bl + 2048 + w * 512;

  for (int k0 = 0; k0 < 64; k0 += 32) {
    gl_lds16(ag0, la0);
    gl_lds16(ag1, la1);
    gl_lds16(bg0, lb0);
    gl_lds16(bg1, lb1);
    ag0 += 32; ag1 += 32; bg0 += 32; bg1 += 32;
    __syncthreads();
    bf16x8 af[4], bff[4];
#pragma unroll
    for (int i = 0; i < 4; i++) af[i] = *(const bf16x8*)&Al[(wm + i * 16 + lr) * 32 + quad * 8];
#pragma unroll
    for (int j = 0; j < 4; j++) bff[j] = *(const bf16x8*)&Bl[(wn + j * 16 + lr) * 32 + quad * 8];
#pragma unroll
    for (int i = 0; i < 4; i++)
#pragma unroll
      for (int j = 0; j < 4; j++)
        acc[i][j] = __builtin_amdgcn_mfma_f32_16x16x32_bf16(af[i], bff[j], acc[i][j], 0, 0, 0);
    __syncthreads();
  }
  // phase 1b: sigmoid(gate) -> LDS tile in C-layout
#pragma unroll
  for (int i = 0; i < 4; i++)
#pragma unroll
    for (int j = 0; j < 4; j++)
#pragma unroll
      for (int rg = 0; rg < 4; rg++) {
        int row = wm + i * 16 + quad * 4 + rg;
        int col = wn + j * 16 + lr;
        gtile[row * 136 + col] = (bf16)sigmf(acc[i][j][rg]);
      }
  __syncthreads();

  // phase 2: 8 contiguous channels per thread; fully vectorized global access
  int c_loc = (tid & 15) * 8;            // 0..120
  int col_g = ncol0 + c_loc;
  int h = col_g >> 6;
  int d0 = col_g & 63;
  f32x4 lnw0 = *(const f32x4*)(ln_w + col_g);
  f32x4 lnw1 = *(const f32x4*)(ln_w + col_g + 4);
  f32x4 lnb0 = *(const f32x4*)(ln_b + col_g);
  f32x4 lnb1 = *(const f32x4*)(ln_b + col_g + 4);
#pragma unroll
  for (int jj = 0; jj < 8; jj++) {
    int row = jj * 16 + (tid >> 4);
    int row_g = m0 + row;
    int b = row_g >> 11;
    int ch = (row_g & (TSEQ - 1)) >> 5;
    long kvb = ((long)h * TBTOK + row_g) * 64 + d0;
    f32x4 st0 = *(const f32x4*)(kv2 + kvb);
    f32x4 st1 = *(const f32x4*)(kv2 + kvb + 4);
    f32x4 cy0 = {0.f, 0.f, 0.f, 0.f}, cy1 = {0.f, 0.f, 0.f, 0.f};
    if (ch != 0) {
      long lb = ((long)((b * 16 + h) * NCH + ch - 1)) * 64 + d0;
      cy0 = *(const f32x4*)(Lend + lb);
      cy1 = *(const f32x4*)(Lend + lb + 4);
    }
    float pw = Parr[h * TBTOK + row_g];
    float bs = bonus[row_g * HN + h];
    long rb = (long)row_g * CDIM + col_g;
    bf16x8 rf8 = *(const bf16x8*)(r_buf + rb);
    bf16x8 vf8 = *(const bf16x8*)(v_buf + rb);
    bf16x8 g8 = *(const bf16x8*)&gtile[row * 136 + c_loc];
    float xw[8];
#pragma unroll
    for (int q = 0; q < 4; q++) {
      xw[q]     = (st0[q] + pw * cy0[q]) * (float)rf8[q]     + bs * (float)vf8[q];
      xw[4 + q] = (st1[q] + pw * cy1[q]) * (float)rf8[4 + q] + bs * (float)vf8[4 + q];
    }
    float sum = 0.f;
#pragma unroll
    for (int q = 0; q < 8; q++) sum += xw[q];
    float mn = redsum8(sum) * (1.f / 64.f);
    float vs = 0.f;
#pragma unroll
    for (int q = 0; q < 8; q++) {
      xw[q] -= mn;
      vs += xw[q] * xw[q];
    }
    float var = redsum8(vs) * (1.f / 64.f);
    float rq = rsqrtf(var + 1e-5f);
    bf16x8 o8;
#pragma unroll
    for (int q = 0; q < 4; q++) {
      o8[q]     = (bf16)((xw[q] * rq * lnw0[q] + lnb0[q]) * (float)g8[q]);
      o8[4 + q] = (bf16)((xw[4 + q] * rq * lnw1[q] + lnb1[q]) * (float)g8[4 + q]);
    }
    *(bf16x8*)(r_buf + rb) = o8;
  }
}

extern "C" void kernel_launch(void* const* d_in, const int* in_sizes, int n_in,
                              void* d_out, int out_size, void* d_ws, size_t ws_size,
                              hipStream_t stream) {
  const float* x    = (const float*)d_in[0];
  const float* x_r  = (const float*)d_in[1];
  const float* x_w  = (const float*)d_in[2];
  const float* x_k  = (const float*)d_in[3];
  const float* x_v  = (const float*)d_in[4];
  const float* x_a  = (const float*)d_in[5];
  const float* x_g  = (const float*)d_in[6];
  const float* w0   = (const float*)d_in[7];
  const float* w1   = (const float*)d_in[8];
  const float* w2   = (const float*)d_in[9];
  const float* a0   = (const float*)d_in[10];
  const float* a1   = (const float*)d_in[11];
  const float* a2   = (const float*)d_in[12];
  // v0,v1,v2 (13,14,15) unused: v_res_gate is a no-op in the reference
  const float* g1   = (const float*)d_in[16];
  const float* g2   = (const float*)d_in[17];
  const float* k_k  = (const float*)d_in[18];
  const float* r_k  = (const float*)d_in[19];
  const float* Wr   = (const float*)d_in[20];
  const float* Wk   = (const float*)d_in[21];
  const float* Wv   = (const float*)d_in[22];
  const float* Wo   = (const float*)d_in[23];
  const float* ln_w = (const float*)d_in[24];
  const float* ln_b = (const float*)d_in[25];
  float* out = (float*)d_out;

  char* p = (char*)d_ws;
  auto carve = [&](size_t bytes) {
    void* r = (void*)p;
    p += (bytes + 255) & ~(size_t)255;
    return r;
  };
  bf16* WrT = (bf16*)carve(1024 * 1024 * 2);
  bf16* WkT = (bf16*)carve(1024 * 1024 * 2);
  bf16* WvT = (bf16*)carve(1024 * 1024 * 2);
  bf16* WoT = (bf16*)carve(1024 * 1024 * 2);
  bf16* Bcat = (bf16*)carve(192 * 2048 * 2);
  bf16* g2T  = (bf16*)carve(1024 * 64 * 2);
  bf16* w2T  = (bf16*)carve(16 * 64 * 2);
  bf16* a2T  = (bf16*)carve(16 * 64 * 2);
  float* zpad = (float*)carve(64 * 4);
  bf16* t1g   = (bf16*)carve((size_t)TBTOK * 64 * 2);
  bf16* r_buf = (bf16*)carve((size_t)TBTOK * CDIM * 2);
  bf16* k_buf = (bf16*)carve((size_t)TBTOK * CDIM * 2);
  bf16* v_buf = (bf16*)carve((size_t)TBTOK * CDIM * 2);
  float* w_arr = (float*)carve((size_t)TBTOK * HN * 4);
  float* a_arr = (float*)carve((size_t)TBTOK * HN * 4);
  float* bonus = (float*)carve((size_t)TBTOK * HN * 4);
  float* Parr  = (float*)carve((size_t)TBTOK * HN * 4);
  float* Lend  = (float*)carve((size_t)128 * NCH * 64 * 4);
  bf16* xr  = (bf16*)carve((size_t)TBTOK * CDIM * 2);
  bf16* xk  = (bf16*)carve((size_t)TBTOK * CDIM * 2);
  bf16* xv  = (bf16*)carve((size_t)TBTOK * CDIM * 2);
  bf16* xbf = (bf16*)carve((size_t)TBTOK * CDIM * 2);
  float* kv2 = (float*)xv;  // 64MB = xv+xbf, dead before scan1

  // 1. mixcvt + all weight prep
  prep_kern<<<dim3(8192 + 4545), 256, 0, stream>>>(
      x, x_r, x_k, x_v, xr, xk, xv, xbf,
      Wr, Wk, Wv, Wo, w1, a1, g1, x_w, x_a, x_g, g2, w2, a2,
      WrT, WkT, WvT, WoT, Bcat, g2T, w2T, a2T, zpad);
  // 2. LoRA stage1 (merged 192-col GEMM + fused stage2 dots)
  stage1_kern<<<dim3(TBTOK / 64), 256, 0, stream>>>(
      xbf, Bcat, zpad, w2T, a2T, w0, a0, t1g, w_arr, a_arr);
  // 3. r,k,v projections: 768 blocks, XCD-local n-fastest decode.
  gemm256_kern<bf16><<<dim3(768), 512, 0, stream>>>(
      xr, xk, xv, WrT, WkT, WvT, r_buf, k_buf, v_buf, 1024);
  // 4. WKV local scans (CHUNK=32; carry == prev chunk-final state)
  scan1_kern<<<dim3(128 * NCH / 4), 256, 0, stream>>>(
      k_buf, v_buf, r_buf, k_k, r_k, a_arr, w_arr, kv2, Parr, bonus, Lend);
  // 5. gate GEMM + vectorized fixup/groupnorm/gating -> an (into r_buf)
  gate_post_kern<<<dim3(8, TBTOK / 128), 256, 0, stream>>>(
      t1g, g2T, kv2, Parr, Lend, bonus, r_buf, v_buf, ln_w, ln_b);
  // 6. out = an @ Wo  (f32 output)
  gemm256_kern<float><<<dim3(256), 512, 0, stream>>>(
      r_buf, r_buf, r_buf, WoT, WoT, WoT, out, out, out, 1024);
}